// Round 8
// baseline (417.366 us; speedup 1.0000x reference)
//
#include <hip/hip_runtime.h>
#include <hip/hip_bf16.h>

// Problem constants
#define Bn 4
#define Tn 2048
#define Cn 1024
#define Hn 16
#define Dn 64
#define Kdim 1024

typedef __bf16 bf16x8 __attribute__((ext_vector_type(8)));
typedef float f32x4 __attribute__((ext_vector_type(4)));
union B8 { uint4 u; bf16x8 f; ushort s[8]; };

static __device__ __forceinline__ ushort f2bf(float x) {
    __hip_bfloat16 h = __float2bfloat16(x);
    return *(ushort*)&h;
}

#define AS1 __attribute__((address_space(1)))
#define AS3 __attribute__((address_space(3)))

static __device__ __forceinline__ void gload_lds16(const ushort* g, ushort* l) {
    __builtin_amdgcn_global_load_lds((AS1 const uint4*)(const void*)g,
                                     (AS3 uint4*)(void*)l, 16, 0, 0);
}

// ---------------------------------------------------------------------------
// Fused prep: grid.y selects section.
//  y==0 (4096 blocks): X fp32 -> bf16 (layout preserved)
//  y==1 (96x32 via blockIdx.x): qkv_w [K,3C] -> Wqt [3C,K] bf16
//  y==2 (32x32): o_w [K,C] -> Wot [C,K] bf16
// ---------------------------------------------------------------------------
__global__ __launch_bounds__(256) void prep_fused(
    const float* __restrict__ X, const float* __restrict__ qkv_w,
    const float* __restrict__ o_w,
    ushort* __restrict__ Xb, ushort* __restrict__ Wqt, ushort* __restrict__ Wot)
{
    if (blockIdx.y == 0) {
        int i = (blockIdx.x * 256 + threadIdx.x) * 8;
        float4 a = *(const float4*)&X[i];
        float4 b = *(const float4*)&X[i + 4];
        ushort4 o0, o1;
        o0.x = f2bf(a.x); o0.y = f2bf(a.y); o0.z = f2bf(a.z); o0.w = f2bf(a.w);
        o1.x = f2bf(b.x); o1.y = f2bf(b.y); o1.z = f2bf(b.z); o1.w = f2bf(b.w);
        *(ushort4*)&Xb[i] = o0;
        *(ushort4*)&Xb[i + 4] = o1;
        return;
    }
    // transpose sections
    const float* W; ushort* Wt; int N, bx;
    if (blockIdx.y == 1) { W = qkv_w; Wt = Wqt; N = 3 * Cn; bx = blockIdx.x; }
    else                 { W = o_w;   Wt = Wot; N = Cn;     bx = blockIdx.x; }
    if (bx >= (N / 32) * 32) return;
    const int n0 = (bx % (N / 32)) * 32, k0 = (bx / (N / 32)) * 32;
    __shared__ float Ls[32][33];
    const int tx = threadIdx.x & 31, ty = threadIdx.x >> 5;
    #pragma unroll
    for (int i = 0; i < 4; i++) {
        int r = ty + i * 8;
        Ls[r][tx] = W[(size_t)(k0 + r) * N + n0 + tx];
    }
    __syncthreads();
    #pragma unroll
    for (int i = 0; i < 4; i++) {
        int r = ty + i * 8;
        Wt[(size_t)(n0 + r) * Kdim + k0 + tx] = f2bf(Ls[tx][r]);
    }
}

// ---------------------------------------------------------------------------
// bf16 MFMA GEMM (m97 structure): C[M,N] = A[M,K] @ Bt[N,K]^T (+bias).
// Bijective XCD swizzle (T1, kept from r19: ~+2us): contiguous grid chunk
// per XCD -> A panel L2-resident per XCD. nwg % 8 == 0 (1536, 512).
// EPI 0: fp32 out + bias.
// EPI 1: bf16 Q[B,H,T,D] (pre-scaled by D^-0.5*log2(e)), K[B,H,T,D],
//        V^T[B,H,D,T]. Epilogue round-trips each wave's 64x64 tile through
//        LDS (XOR bank swizzle) -> fully coalesced uint4 global stores.
// ---------------------------------------------------------------------------
template <int EPI>
__global__ __launch_bounds__(256) void gemm_bt(
    const ushort* __restrict__ A, const ushort* __restrict__ Bt,
    const float* __restrict__ bias,
    float* __restrict__ Out, ushort* __restrict__ Qb,
    ushort* __restrict__ Kb, ushort* __restrict__ Vtb)
{
    // XCD-aware bijective swizzle: contiguous grid chunk per XCD.
    const int nbx = gridDim.x;
    const int nwg = nbx * gridDim.y;
    const int bid = blockIdx.y * nbx + blockIdx.x;
    const int cpx = nwg >> 3;                 // nwg % 8 == 0 for our grids
    const int wg  = (bid & 7) * cpx + (bid >> 3);
    const int m0 = (wg / nbx) * 128;
    const int n0 = (wg % nbx) * 128;
    const int t  = threadIdx.x;
    const int wave = t >> 6, lane = t & 63;
    const int ln = lane & 15, quad = lane >> 4;
    const int wm = wave >> 1, wn = wave & 1;

    __shared__ ushort As[128 * 64];
    __shared__ ushort Bs[128 * 64];

    f32x4 acc[4][4] = {};

    for (int k0 = 0; k0 < Kdim; k0 += 64) {
        __syncthreads();
        #pragma unroll
        for (int it = 0; it < 4; it++) {
            int c = it * 256 + wave * 64 + lane;
            int row = c >> 3, seg = c & 7;
            int gseg = seg ^ (row & 7);
            gload_lds16(&A [(size_t)(m0 + row) * Kdim + k0 + gseg * 8], &As[c * 8]);
            gload_lds16(&Bt[(size_t)(n0 + row) * Kdim + k0 + gseg * 8], &Bs[c * 8]);
        }
        __syncthreads();

        #pragma unroll
        for (int ks = 0; ks < 2; ks++) {
            bf16x8 af[4], bf[4];
            #pragma unroll
            for (int mm = 0; mm < 4; mm++) {
                int row = wm * 64 + mm * 16 + ln;
                int seg = (ks * 4 + quad) ^ (ln & 7);
                B8 tmp; tmp.u = *(const uint4*)&As[row * 64 + seg * 8];
                af[mm] = tmp.f;
            }
            #pragma unroll
            for (int nn = 0; nn < 4; nn++) {
                int row = wn * 64 + nn * 16 + ln;
                int seg = (ks * 4 + quad) ^ (ln & 7);
                B8 tmp; tmp.u = *(const uint4*)&Bs[row * 64 + seg * 8];
                bf[nn] = tmp.f;
            }
            #pragma unroll
            for (int mm = 0; mm < 4; mm++)
                #pragma unroll
                for (int nn = 0; nn < 4; nn++)
                    acc[mm][nn] = __builtin_amdgcn_mfma_f32_16x16x32_bf16(
                        af[mm], bf[nn], acc[mm][nn], 0, 0, 0);
        }
    }

    if (EPI == 0) {
        #pragma unroll
        for (int nn = 0; nn < 4; nn++) {
            int n = n0 + wn * 64 + nn * 16 + ln;
            float bv = bias[n];
            #pragma unroll
            for (int mm = 0; mm < 4; mm++) {
                int mbase = m0 + wm * 64 + mm * 16 + quad * 4;
                #pragma unroll
                for (int reg = 0; reg < 4; reg++)
                    Out[(size_t)(mbase + reg) * 1024 + n] = acc[mm][nn][reg] + bv;
            }
        }
    } else {
        const int nb = n0 + wn * 64;
        const int which = nb >> 10;            // 0=Q 1=K 2=V
        const int h = (nb & 1023) >> 6;
        const float scale = (which == 0) ? 0.125f * 1.44269504088896f : 1.0f;
        const int b_ = m0 >> 11;               // 128-row tile within one batch
        const int t0 = (m0 & 2047) + wm * 64;

        __syncthreads();   // fragments consumed; reuse As/Bs as transpose pads
        ushort* tile = ((wave & 2) ? Bs : As) + (wave & 1) * 4096;  // 64x64/wave

        if (which == 2) {
            // LDS tile [n=d][m=token] (XOR-swizzled), rows -> [B,H,D,T]
            #pragma unroll
            for (int nn = 0; nn < 4; nn++) {
                float bv = bias[nb + nn * 16 + ln];
                #pragma unroll
                for (int mm = 0; mm < 4; mm++)
                    #pragma unroll
                    for (int reg = 0; reg < 4; reg++) {
                        int m = mm * 16 + quad * 4 + reg;
                        int n = nn * 16 + ln;
                        tile[n * 64 + (m ^ (((n >> 1) & 7) * 8))] =
                            f2bf(acc[mm][nn][reg] + bv);
                    }
            }
            #pragma unroll
            for (int it = 0; it < 8; it++) {
                int idx = it * 64 + lane;
                int row = idx >> 3, seg = idx & 7;   // row = d, seg = token/8
                uint4 v = *(const uint4*)&tile[row * 64 +
                              ((seg * 8) ^ (((row >> 1) & 7) * 8))];
                *(uint4*)&Vtb[((size_t)((b_ * Hn + h) * Dn) + row) * Tn + t0 + seg * 8] = v;
            }
        } else {
            // LDS tile [m=token][n=d] (XOR-swizzled), rows -> [B,H,T,D]
            ushort* dst = (which == 0) ? Qb : Kb;
            #pragma unroll
            for (int nn = 0; nn < 4; nn++) {
                float bv = bias[nb + nn * 16 + ln];
                #pragma unroll
                for (int mm = 0; mm < 4; mm++)
                    #pragma unroll
                    for (int reg = 0; reg < 4; reg++) {
                        int m = mm * 16 + quad * 4 + reg;
                        int n = nn * 16 + ln;
                        tile[m * 64 + (n ^ (((m >> 1) & 7) * 8))] =
                            f2bf((acc[mm][nn][reg] + bv) * scale);
                    }
            }
            #pragma unroll
            for (int it = 0; it < 8; it++) {
                int idx = it * 64 + lane;
                int row = idx >> 3, seg = idx & 7;   // row = token, seg = d/8
                uint4 v = *(const uint4*)&tile[row * 64 +
                              ((seg * 8) ^ (((row >> 1) & 7) * 8))];
                *(uint4*)&dst[((size_t)((b_ * Hn + h) * Tn) + t0 + row) * Dn + seg * 8] = v;
            }
        }
    }
}

// ---------------------------------------------------------------------------
// Flash attention (r20): r18 serial-cut structure (98.6us proven; setprio
// REVERTED — r19 showed -11us in this barrier-lockstep block), now at
// 3 blocks/CU: Ps halved to [wave][slot(2)][ns][16*34] = 17.4KB by
// ping-ponging the P roundtrip in two batches of 2 passes (DS ops are
// per-wave in-order, so batch-1 writes cannot pass batch-0's pending
// reads). LDS = Ks 32KB + Ps 17.4KB = 50.2KB -> 3 blocks/CU.
// Grid: triangular (64,16) = 1024 blocks, heavy-first (qt = 15-y), so the
// 3rd resident slot is actually used; launch_bounds(256,3) -> ~170 VGPR
// budget, no spill. Cost: 2 lgkm roundtrip waits per chunk instead of 1.
//  - Batched P roundtrip, exp2-with-m_old before rare defer-max rescale,
//    v_cvt_pk_bf16_f32 packing, ones-MFMA row-sum, tree max (all r18).
// ---------------------------------------------------------------------------
__global__ __launch_bounds__(256, 3) void attn_mfma(
    const ushort* __restrict__ Qb, const ushort* __restrict__ Kb,
    const ushort* __restrict__ Vtb, ushort* __restrict__ Ob)
{
    const int bh   = blockIdx.x;       // 0..63 (fastest-varying)
    const int qt   = 15 - blockIdx.y;  // heavy tiles dispatched first
    const int t    = threadIdx.x;
    const int wave = t >> 6, lane = t & 63;
    const int ln   = lane & 15, quad = lane >> 4;

    __shared__ ushort Ks[2][128 * 64];       // [key][d], xor-swizzled segs
    __shared__ ushort Ps[4][2][2][16 * 34];  // [wave][slot][ns][q(16)*34]

    const ushort* KgB = Kb  + (size_t)bh * Tn * Dn;
    const ushort* VgB = Vtb + (size_t)bh * Dn * Tn;
    const int b_ = bh >> 4, h = bh & 15;

    // all-ones bf16 A-fragment for the l row-sum MFMA
    B8 ones;
    #pragma unroll
    for (int j = 0; j < 8; j++) ones.s[j] = 0x3F80;

    #define STAGE_K(kc, buf)                                                   \
        do {                                                                   \
            _Pragma("unroll")                                                  \
            for (int it = 0; it < 4; it++) {                                   \
                int c = it * 256 + wave * 64 + lane;                           \
                int row = c >> 3, seg = c & 7;                                 \
                int gs = seg ^ (row & 7);                                      \
                gload_lds16(&KgB[(size_t)((kc) * 128 + row) * Dn + gs * 8],    \
                            &Ks[buf][c * 8]);                                  \
            }                                                                  \
        } while (0)

    int cur = 0;
    STAGE_K(0, 0);

    const int q0 = qt * 128;
    const ushort* Qg = Qb + ((size_t)bh * Tn + q0 + wave * 32) * Dn;
    bf16x8 qf[2][2];
    #pragma unroll
    for (int ns = 0; ns < 2; ns++)
        #pragma unroll
        for (int ks = 0; ks < 2; ks++) {
            B8 tmp; tmp.u = *(const uint4*)&Qg[(ns * 16 + ln) * 64 + ks * 32 + quad * 8];
            qf[ns][ks] = tmp.f;
        }

    f32x4 Oacc[4][2] = {};   // O^T [d-subtile][ns], lane ln = q
    f32x4 Lacc[2] = {};      // row-sum accumulator (rows replicated)
    float m_r[2] = {0.f, 0.f};   // init 0: exp2-first scheme needs finite S-m

    for (int kc = 0; kc <= qt; kc++) {
        __syncthreads();   // publishes K(kc); drains prefetch issued last iter

        // V^T fragments: direct global->VGPR, A-layout natural in [B,H,D,T]
        B8 vfr[4][4];      // [d-subtile][32-key step]
        #pragma unroll
        for (int gks = 0; gks < 4; gks++)
            #pragma unroll
            for (int ctd = 0; ctd < 4; ctd++)
                vfr[ctd][gks].u = *(const uint4*)&VgB[
                    (size_t)(ctd * 16 + ln) * Tn + kc * 128 + gks * 32 + quad * 8];

        if (kc < qt) STAGE_K(kc + 1, cur ^ 1);   // prefetch next chunk

        // S^T = K Q^T: rows = keys (128 = 8 ct), cols = q (32 = 2 ns)
        const ushort* Kc = Ks[cur];
        f32x4 S[8][2] = {};
        #pragma unroll
        for (int ks = 0; ks < 2; ks++)
            #pragma unroll
            for (int ct = 0; ct < 8; ct++) {
                B8 a; a.u = *(const uint4*)&Kc[(ct * 16 + ln) * 64 +
                                               (((ks * 4 + quad) ^ (ln & 7)) * 8)];
                #pragma unroll
                for (int ns = 0; ns < 2; ns++)
                    S[ct][ns] = __builtin_amdgcn_mfma_f32_16x16x32_bf16(
                        a.f, qf[ns][ks], S[ct][ns], 0, 0, 0);
            }

        if (kc == qt) {   // causal mask on diagonal chunk
            #pragma unroll
            for (int ct = 0; ct < 8; ct++) {
                int keyl = ct * 16 + quad * 4;
                #pragma unroll
                for (int ns = 0; ns < 2; ns++) {
                    int ql = wave * 32 + ns * 16 + ln;
                    #pragma unroll
                    for (int reg = 0; reg < 4; reg++)
                        if (keyl + reg > ql) S[ct][ns][reg] = -1e30f;
                }
            }
        }

        // per-lane chunk max (tree), reduce over quads
        float pm[2], m_old[2];
        #pragma unroll
        for (int ns = 0; ns < 2; ns++) {
            m_old[ns] = m_r[ns];
            float ctm[8];
            #pragma unroll
            for (int ct = 0; ct < 8; ct++)
                ctm[ct] = fmaxf(fmaxf(S[ct][ns][0], S[ct][ns][1]),
                                fmaxf(S[ct][ns][2], S[ct][ns][3]));
            float p = fmaxf(fmaxf(fmaxf(ctm[0], ctm[1]), fmaxf(ctm[2], ctm[3])),
                            fmaxf(fmaxf(ctm[4], ctm[5]), fmaxf(ctm[6], ctm[7])));
            p = fmaxf(p, __shfl_xor(p, 16));
            p = fmaxf(p, __shfl_xor(p, 32));
            pm[ns] = p;
        }

        // exp2 with OLD max — independent of the shuffle chain above, so
        // the scheduler overlaps the 64 trans ops with shuffle latency.
        // Safe: S - m_old <= ~20 << 128 (m_old >= 0), masked -> exp2 -> 0.
        #pragma unroll
        for (int ns = 0; ns < 2; ns++)
            #pragma unroll
            for (int ct = 0; ct < 8; ct++)
                #pragma unroll
                for (int reg = 0; reg < 4; reg++)
                    S[ct][ns][reg] = exp2f(S[ct][ns][reg] - m_old[ns]);

        // defer-max: rescale only when some lane's max grew by > 8 (log2)
        bool need = (pm[0] > m_old[0] + 8.0f) | (pm[1] > m_old[1] + 8.0f);
        if (__any(need)) {
            #pragma unroll
            for (int ns = 0; ns < 2; ns++) {
                float mn = fmaxf(m_old[ns], pm[ns]);
                float alpha = exp2f(m_old[ns] - mn);
                m_r[ns] = mn;
                #pragma unroll
                for (int ct = 0; ct < 8; ct++)
                    #pragma unroll
                    for (int reg = 0; reg < 4; reg++)
                        S[ct][ns][reg] *= alpha;
                #pragma unroll
                for (int ctd = 0; ctd < 4; ctd++)
                    Oacc[ctd][ns] *= alpha;
                Lacc[ns] *= alpha;
            }
        }

        // Two batches: {pack+write passes 2b,2b+1} -> one wait -> {PV both}.
        // Slot = p&1; batch-1 writes reuse slots only after batch-0 reads
        // (DS per-wave in-order + program order -> WAR safe).
        #pragma unroll
        for (int b2 = 0; b2 < 2; b2++) {
            #pragma unroll
            for (int pp = 0; pp < 2; pp++) {
                int p = b2 * 2 + pp;
                #pragma unroll
                for (int ns = 0; ns < 2; ns++)
                    #pragma unroll
                    for (int cth = 0; cth < 2; cth++) {
                        int ct = p * 2 + cth;
                        float s0 = S[ct][ns][0], s1 = S[ct][ns][1];
                        float s2 = S[ct][ns][2], s3 = S[ct][ns][3];
                        uint w0, w1;
                        asm("v_cvt_pk_bf16_f32 %0, %1, %2" : "=v"(w0) : "v"(s0), "v"(s1));
                        asm("v_cvt_pk_bf16_f32 %0, %1, %2" : "=v"(w1) : "v"(s2), "v"(s3));
                        uint2 o; o.x = w0; o.y = w1;
                        *(uint2*)&Ps[wave][pp][ns]
                            [ln * 34 + cth * 16 + quad * 4] = o;
                    }
            }
            #pragma unroll
            for (int pp = 0; pp < 2; pp++) {
                int p = b2 * 2 + pp;
                #pragma unroll
                for (int ns = 0; ns < 2; ns++) {
                    B8 pfr; pfr.u = *(const uint4*)&Ps[wave][pp][ns]
                        [ln * 34 + quad * 8];
                    #pragma unroll
                    for (int ctd = 0; ctd < 4; ctd++)
                        Oacc[ctd][ns] = __builtin_amdgcn_mfma_f32_16x16x32_bf16(
                            vfr[ctd][p].f, pfr.f, Oacc[ctd][ns], 0, 0, 0);
                    Lacc[ns] = __builtin_amdgcn_mfma_f32_16x16x32_bf16(
                        ones.f, pfr.f, Lacc[ns], 0, 0, 0);
                }
            }
        }
        cur ^= 1;
    }

    // epilogue: bf16 attn_out [B*T][C]; lane ln = token, regs = d
    #pragma unroll
    for (int ns = 0; ns < 2; ns++) {
        float inv = 1.0f / Lacc[ns][0];
        int token = q0 + wave * 32 + ns * 16 + ln;
        ushort* dst = Ob + ((size_t)(b_ * Tn + token)) * Cn + h * 64;
        #pragma unroll
        for (int ctd = 0; ctd < 4; ctd++) {
            ushort4 o;
            #pragma unroll
            for (int reg = 0; reg < 4; reg++)
                ((ushort*)&o)[reg] = f2bf(Oacc[ctd][ns][reg] * inv);
            *(ushort4*)&dst[ctd * 16 + quad * 4] = o;
        }
    }
    #undef STAGE_K
}

// ---------------------------------------------------------------------------
extern "C" void kernel_launch(void* const* d_in, const int* in_sizes, int n_in,
                              void* d_out, int out_size, void* d_ws, size_t ws_size,
                              hipStream_t stream) {
    const float* X     = (const float*)d_in[0];
    const float* qkv_w = (const float*)d_in[1];
    const float* qkv_b = (const float*)d_in[2];
    const float* o_w   = (const float*)d_in[3];
    const float* o_b   = (const float*)d_in[4];
    float* out = (float*)d_out;

    const size_t BTC = (size_t)Bn * Tn * Cn;     // 8388608
    ushort* Xb  = (ushort*)d_ws;                 // bf16 [8192,1024]
    ushort* Wqt = Xb  + BTC;                     // bf16 [3072,1024]
    ushort* Wot = Wqt + 3 * Cn * Cn;             // bf16 [1024,1024]
    ushort* Qb  = Wot + Cn * Cn;                 // bf16 [B,H,T,D]
    ushort* Kb  = Qb  + BTC;
    ushort* Vtb = Kb  + BTC;                     // bf16 [B,H,D,T]
    ushort* Ao  = Vtb + BTC;                     // bf16 [B*T,C]

    // fused prep: y=0 cast (4096 blocks), y=1 qkv_w transpose (96*32=3072),
    // y=2 o_w transpose (32*32=1024). grid.x = max section size.
    prep_fused<<<dim3(4096, 3), 256, 0, stream>>>(X, qkv_w, o_w, Xb, Wqt, Wot);

    gemm_bt<1><<<dim3(3 * Cn / 128, 8192 / 128), 256, 0, stream>>>(
        Xb, Wqt, qkv_b, nullptr, Qb, Kb, Vtb);
    attn_mfma<<<dim3(Bn * Hn, 16), 256, 0, stream>>>(Qb, Kb, Vtb, Ao);
    gemm_bt<0><<<dim3(Cn / 128, 8192 / 128), 256, 0, stream>>>(
        Ao, Wot, o_b, out, nullptr, nullptr, nullptr);
}

// Round 9
// 269.786 us; speedup vs baseline: 1.5470x; 1.5470x over previous
//
#include <hip/hip_runtime.h>
#include <hip/hip_bf16.h>

// Problem constants
#define Bn 4
#define Tn 2048
#define Cn 1024
#define Hn 16
#define Dn 64
#define Kdim 1024

typedef __bf16 bf16x8 __attribute__((ext_vector_type(8)));
typedef float f32x4 __attribute__((ext_vector_type(4)));
union B8 { uint4 u; bf16x8 f; ushort s[8]; };

static __device__ __forceinline__ ushort f2bf(float x) {
    __hip_bfloat16 h = __float2bfloat16(x);
    return *(ushort*)&h;
}

#define AS1 __attribute__((address_space(1)))
#define AS3 __attribute__((address_space(3)))

static __device__ __forceinline__ void gload_lds16(const ushort* g, ushort* l) {
    __builtin_amdgcn_global_load_lds((AS1 const uint4*)(const void*)g,
                                     (AS3 uint4*)(void*)l, 16, 0, 0);
}

// ---------------------------------------------------------------------------
// Fused prep: grid.y selects section.
//  y==0 (4096 blocks): X fp32 -> bf16 (layout preserved)
//  y==1 (96x32 via blockIdx.x): qkv_w [K,3C] -> Wqt [3C,K] bf16
//  y==2 (32x32): o_w [K,C] -> Wot [C,K] bf16
// ---------------------------------------------------------------------------
__global__ __launch_bounds__(256) void prep_fused(
    const float* __restrict__ X, const float* __restrict__ qkv_w,
    const float* __restrict__ o_w,
    ushort* __restrict__ Xb, ushort* __restrict__ Wqt, ushort* __restrict__ Wot)
{
    if (blockIdx.y == 0) {
        int i = (blockIdx.x * 256 + threadIdx.x) * 8;
        float4 a = *(const float4*)&X[i];
        float4 b = *(const float4*)&X[i + 4];
        ushort4 o0, o1;
        o0.x = f2bf(a.x); o0.y = f2bf(a.y); o0.z = f2bf(a.z); o0.w = f2bf(a.w);
        o1.x = f2bf(b.x); o1.y = f2bf(b.y); o1.z = f2bf(b.z); o1.w = f2bf(b.w);
        *(ushort4*)&Xb[i] = o0;
        *(ushort4*)&Xb[i + 4] = o1;
        return;
    }
    // transpose sections
    const float* W; ushort* Wt; int N, bx;
    if (blockIdx.y == 1) { W = qkv_w; Wt = Wqt; N = 3 * Cn; bx = blockIdx.x; }
    else                 { W = o_w;   Wt = Wot; N = Cn;     bx = blockIdx.x; }
    if (bx >= (N / 32) * 32) return;
    const int n0 = (bx % (N / 32)) * 32, k0 = (bx / (N / 32)) * 32;
    __shared__ float Ls[32][33];
    const int tx = threadIdx.x & 31, ty = threadIdx.x >> 5;
    #pragma unroll
    for (int i = 0; i < 4; i++) {
        int r = ty + i * 8;
        Ls[r][tx] = W[(size_t)(k0 + r) * N + n0 + tx];
    }
    __syncthreads();
    #pragma unroll
    for (int i = 0; i < 4; i++) {
        int r = ty + i * 8;
        Wt[(size_t)(n0 + r) * Kdim + k0 + tx] = f2bf(Ls[tx][r]);
    }
}

// ---------------------------------------------------------------------------
// bf16 MFMA GEMM (m97 structure): C[M,N] = A[M,K] @ Bt[N,K]^T (+bias).
// Bijective XCD swizzle (T1): contiguous grid chunk per XCD -> A panel
// L2-resident per XCD. nwg % 8 == 0 (1536, 512).
// EPI 0: fp32 out + bias.
// EPI 1: bf16 Q[B,H,T,D] (pre-scaled by D^-0.5*log2(e)), K[B,H,T,D],
//        V^T[B,H,D,T]. Epilogue round-trips each wave's 64x64 tile through
//        LDS (XOR bank swizzle) -> fully coalesced uint4 global stores.
// ---------------------------------------------------------------------------
template <int EPI>
__global__ __launch_bounds__(256) void gemm_bt(
    const ushort* __restrict__ A, const ushort* __restrict__ Bt,
    const float* __restrict__ bias,
    float* __restrict__ Out, ushort* __restrict__ Qb,
    ushort* __restrict__ Kb, ushort* __restrict__ Vtb)
{
    // XCD-aware bijective swizzle: contiguous grid chunk per XCD.
    const int nbx = gridDim.x;
    const int nwg = nbx * gridDim.y;
    const int bid = blockIdx.y * nbx + blockIdx.x;
    const int cpx = nwg >> 3;                 // nwg % 8 == 0 for our grids
    const int wg  = (bid & 7) * cpx + (bid >> 3);
    const int m0 = (wg / nbx) * 128;
    const int n0 = (wg % nbx) * 128;
    const int t  = threadIdx.x;
    const int wave = t >> 6, lane = t & 63;
    const int ln = lane & 15, quad = lane >> 4;
    const int wm = wave >> 1, wn = wave & 1;

    __shared__ ushort As[128 * 64];
    __shared__ ushort Bs[128 * 64];

    f32x4 acc[4][4] = {};

    for (int k0 = 0; k0 < Kdim; k0 += 64) {
        __syncthreads();
        #pragma unroll
        for (int it = 0; it < 4; it++) {
            int c = it * 256 + wave * 64 + lane;
            int row = c >> 3, seg = c & 7;
            int gseg = seg ^ (row & 7);
            gload_lds16(&A [(size_t)(m0 + row) * Kdim + k0 + gseg * 8], &As[c * 8]);
            gload_lds16(&Bt[(size_t)(n0 + row) * Kdim + k0 + gseg * 8], &Bs[c * 8]);
        }
        __syncthreads();

        #pragma unroll
        for (int ks = 0; ks < 2; ks++) {
            bf16x8 af[4], bf[4];
            #pragma unroll
            for (int mm = 0; mm < 4; mm++) {
                int row = wm * 64 + mm * 16 + ln;
                int seg = (ks * 4 + quad) ^ (ln & 7);
                B8 tmp; tmp.u = *(const uint4*)&As[row * 64 + seg * 8];
                af[mm] = tmp.f;
            }
            #pragma unroll
            for (int nn = 0; nn < 4; nn++) {
                int row = wn * 64 + nn * 16 + ln;
                int seg = (ks * 4 + quad) ^ (ln & 7);
                B8 tmp; tmp.u = *(const uint4*)&Bs[row * 64 + seg * 8];
                bf[nn] = tmp.f;
            }
            #pragma unroll
            for (int mm = 0; mm < 4; mm++)
                #pragma unroll
                for (int nn = 0; nn < 4; nn++)
                    acc[mm][nn] = __builtin_amdgcn_mfma_f32_16x16x32_bf16(
                        af[mm], bf[nn], acc[mm][nn], 0, 0, 0);
        }
    }

    if (EPI == 0) {
        #pragma unroll
        for (int nn = 0; nn < 4; nn++) {
            int n = n0 + wn * 64 + nn * 16 + ln;
            float bv = bias[n];
            #pragma unroll
            for (int mm = 0; mm < 4; mm++) {
                int mbase = m0 + wm * 64 + mm * 16 + quad * 4;
                #pragma unroll
                for (int reg = 0; reg < 4; reg++)
                    Out[(size_t)(mbase + reg) * 1024 + n] = acc[mm][nn][reg] + bv;
            }
        }
    } else {
        const int nb = n0 + wn * 64;
        const int which = nb >> 10;            // 0=Q 1=K 2=V
        const int h = (nb & 1023) >> 6;
        const float scale = (which == 0) ? 0.125f * 1.44269504088896f : 1.0f;
        const int b_ = m0 >> 11;               // 128-row tile within one batch
        const int t0 = (m0 & 2047) + wm * 64;

        __syncthreads();   // fragments consumed; reuse As/Bs as transpose pads
        ushort* tile = ((wave & 2) ? Bs : As) + (wave & 1) * 4096;  // 64x64/wave

        if (which == 2) {
            // LDS tile [n=d][m=token] (XOR-swizzled), rows -> [B,H,D,T]
            #pragma unroll
            for (int nn = 0; nn < 4; nn++) {
                float bv = bias[nb + nn * 16 + ln];
                #pragma unroll
                for (int mm = 0; mm < 4; mm++)
                    #pragma unroll
                    for (int reg = 0; reg < 4; reg++) {
                        int m = mm * 16 + quad * 4 + reg;
                        int n = nn * 16 + ln;
                        tile[n * 64 + (m ^ (((n >> 1) & 7) * 8))] =
                            f2bf(acc[mm][nn][reg] + bv);
                    }
            }
            #pragma unroll
            for (int it = 0; it < 8; it++) {
                int idx = it * 64 + lane;
                int row = idx >> 3, seg = idx & 7;   // row = d, seg = token/8
                uint4 v = *(const uint4*)&tile[row * 64 +
                              ((seg * 8) ^ (((row >> 1) & 7) * 8))];
                *(uint4*)&Vtb[((size_t)((b_ * Hn + h) * Dn) + row) * Tn + t0 + seg * 8] = v;
            }
        } else {
            // LDS tile [m=token][n=d] (XOR-swizzled), rows -> [B,H,T,D]
            ushort* dst = (which == 0) ? Qb : Kb;
            #pragma unroll
            for (int nn = 0; nn < 4; nn++) {
                float bv = bias[nb + nn * 16 + ln];
                #pragma unroll
                for (int mm = 0; mm < 4; mm++)
                    #pragma unroll
                    for (int reg = 0; reg < 4; reg++) {
                        int m = mm * 16 + quad * 4 + reg;
                        int n = nn * 16 + ln;
                        tile[m * 64 + (n ^ (((m >> 1) & 7) * 8))] =
                            f2bf((acc[mm][nn][reg] + bv) * scale);
                    }
            }
            #pragma unroll
            for (int it = 0; it < 8; it++) {
                int idx = it * 64 + lane;
                int row = idx >> 3, seg = idx & 7;   // row = token, seg = d/8
                uint4 v = *(const uint4*)&tile[row * 64 +
                              ((seg * 8) ^ (((row >> 1) & 7) * 8))];
                *(uint4*)&dst[((size_t)((b_ * Hn + h) * Tn) + t0 + row) * Dn + seg * 8] = v;
            }
        }
    }
}

// ---------------------------------------------------------------------------
// Flash attention (r21 = r18 verbatim, the 98.6us verified best):
// 128-row q-tiles paired (15-y, y) -> 17 chunks/block, grid (64,8) = 512
// balanced blocks = 2/CU, 32 q per wave. Serial-path cuts:
//  1. Batched P roundtrip (one lgkm wait per chunk).
//  2. exp2 with m_old before the (rare) defer-max rescale branch.
//  3. v_cvt_pk_bf16_f32 packing.
// Softmax row-sum via ones-MFMA; defer-max THR=8 (log2); tree max.
// LDS = Ks 32KB + Ps 34KB = 67.6KB -> 2 blocks/CU.
// SETTLED: setprio hurts here (r19, -11us: barrier-lockstep waves).
// (256,3)/(256,4) spill BOTH register-file halves (r20/r14-16): allocator
// splits budget ~evenly arch/acc; AGPR demand 104 and arch demand ~128
// both need the full 128/128 of (256,2). Occupancy 2 is structural.
// ---------------------------------------------------------------------------
__global__ __launch_bounds__(256, 2) void attn_mfma(
    const ushort* __restrict__ Qb, const ushort* __restrict__ Kb,
    const ushort* __restrict__ Vtb, ushort* __restrict__ Ob)
{
    const int bh   = blockIdx.x;       // 0..63 (fastest-varying)
    const int yp   = blockIdx.y;       // 0..7: pair (15-yp, yp)
    const int t    = threadIdx.x;
    const int wave = t >> 6, lane = t & 63;
    const int ln   = lane & 15, quad = lane >> 4;

    __shared__ ushort Ks[2][128 * 64];       // [key][d], xor-swizzled segs
    __shared__ ushort Ps[4][2][4][16 * 34];  // [wave][ns][pass][q(16)*34]

    const ushort* KgB = Kb  + (size_t)bh * Tn * Dn;
    const ushort* VgB = Vtb + (size_t)bh * Dn * Tn;
    const int b_ = bh >> 4, h = bh & 15;

    // all-ones bf16 A-fragment for the l row-sum MFMA
    B8 ones;
    #pragma unroll
    for (int j = 0; j < 8; j++) ones.s[j] = 0x3F80;

    #define STAGE_K(kc, buf)                                                   \
        do {                                                                   \
            _Pragma("unroll")                                                  \
            for (int it = 0; it < 4; it++) {                                   \
                int c = it * 256 + wave * 64 + lane;                           \
                int row = c >> 3, seg = c & 7;                                 \
                int gs = seg ^ (row & 7);                                      \
                gload_lds16(&KgB[(size_t)((kc) * 128 + row) * Dn + gs * 8],    \
                            &Ks[buf][c * 8]);                                  \
            }                                                                  \
        } while (0)

    for (int pass = 0; pass < 2; pass++) {
        const int qt = pass ? yp : 15 - yp;
        if (pass) __syncthreads();     // protect Ks reuse from pass-0 readers

        int cur = 0;
        STAGE_K(0, 0);

        const int q0 = qt * 128;
        const ushort* Qg = Qb + ((size_t)bh * Tn + q0 + wave * 32) * Dn;
        bf16x8 qf[2][2];
        #pragma unroll
        for (int ns = 0; ns < 2; ns++)
            #pragma unroll
            for (int ks = 0; ks < 2; ks++) {
                B8 tmp; tmp.u = *(const uint4*)&Qg[(ns * 16 + ln) * 64 + ks * 32 + quad * 8];
                qf[ns][ks] = tmp.f;
            }

        f32x4 Oacc[4][2] = {};   // O^T [d-subtile][ns], lane ln = q
        f32x4 Lacc[2] = {};      // row-sum accumulator (rows replicated)
        float m_r[2] = {0.f, 0.f};   // init 0: exp2-first scheme needs finite S-m

        for (int kc = 0; kc <= qt; kc++) {
            __syncthreads();   // publishes K(kc); drains prefetch issued last iter

            // V^T fragments: direct global->VGPR, A-layout natural in [B,H,D,T]
            B8 vfr[4][4];      // [d-subtile][32-key step]
            #pragma unroll
            for (int gks = 0; gks < 4; gks++)
                #pragma unroll
                for (int ctd = 0; ctd < 4; ctd++)
                    vfr[ctd][gks].u = *(const uint4*)&VgB[
                        (size_t)(ctd * 16 + ln) * Tn + kc * 128 + gks * 32 + quad * 8];

            if (kc < qt) STAGE_K(kc + 1, cur ^ 1);   // prefetch next chunk

            // S^T = K Q^T: rows = keys (128 = 8 ct), cols = q (32 = 2 ns)
            const ushort* Kc = Ks[cur];
            f32x4 S[8][2] = {};
            #pragma unroll
            for (int ks = 0; ks < 2; ks++)
                #pragma unroll
                for (int ct = 0; ct < 8; ct++) {
                    B8 a; a.u = *(const uint4*)&Kc[(ct * 16 + ln) * 64 +
                                                   (((ks * 4 + quad) ^ (ln & 7)) * 8)];
                    #pragma unroll
                    for (int ns = 0; ns < 2; ns++)
                        S[ct][ns] = __builtin_amdgcn_mfma_f32_16x16x32_bf16(
                            a.f, qf[ns][ks], S[ct][ns], 0, 0, 0);
                }

            if (kc == qt) {   // causal mask on diagonal chunk
                #pragma unroll
                for (int ct = 0; ct < 8; ct++) {
                    int keyl = ct * 16 + quad * 4;
                    #pragma unroll
                    for (int ns = 0; ns < 2; ns++) {
                        int ql = wave * 32 + ns * 16 + ln;
                        #pragma unroll
                        for (int reg = 0; reg < 4; reg++)
                            if (keyl + reg > ql) S[ct][ns][reg] = -1e30f;
                    }
                }
            }

            // per-lane chunk max (tree), reduce over quads
            float pm[2], m_old[2];
            #pragma unroll
            for (int ns = 0; ns < 2; ns++) {
                m_old[ns] = m_r[ns];
                float ctm[8];
                #pragma unroll
                for (int ct = 0; ct < 8; ct++)
                    ctm[ct] = fmaxf(fmaxf(S[ct][ns][0], S[ct][ns][1]),
                                    fmaxf(S[ct][ns][2], S[ct][ns][3]));
                float p = fmaxf(fmaxf(fmaxf(ctm[0], ctm[1]), fmaxf(ctm[2], ctm[3])),
                                fmaxf(fmaxf(ctm[4], ctm[5]), fmaxf(ctm[6], ctm[7])));
                p = fmaxf(p, __shfl_xor(p, 16));
                p = fmaxf(p, __shfl_xor(p, 32));
                pm[ns] = p;
            }

            // exp2 with OLD max — independent of the shuffle chain above, so
            // the scheduler overlaps the 64 trans ops with shuffle latency.
            // Safe: S - m_old <= ~20 << 128 (m_old >= 0), masked -> exp2 -> 0.
            #pragma unroll
            for (int ns = 0; ns < 2; ns++)
                #pragma unroll
                for (int ct = 0; ct < 8; ct++)
                    #pragma unroll
                    for (int reg = 0; reg < 4; reg++)
                        S[ct][ns][reg] = exp2f(S[ct][ns][reg] - m_old[ns]);

            // defer-max: rescale only when some lane's max grew by > 8 (log2)
            bool need = (pm[0] > m_old[0] + 8.0f) | (pm[1] > m_old[1] + 8.0f);
            if (__any(need)) {
                #pragma unroll
                for (int ns = 0; ns < 2; ns++) {
                    float mn = fmaxf(m_old[ns], pm[ns]);
                    float alpha = exp2f(m_old[ns] - mn);
                    m_r[ns] = mn;
                    #pragma unroll
                    for (int ct = 0; ct < 8; ct++)
                        #pragma unroll
                        for (int reg = 0; reg < 4; reg++)
                            S[ct][ns][reg] *= alpha;
                    #pragma unroll
                    for (int ctd = 0; ctd < 4; ctd++)
                        Oacc[ctd][ns] *= alpha;
                    Lacc[ns] *= alpha;
                }
            }

            // pack ALL P (v_cvt_pk_bf16_f32) and write all 8 pass-slices,
            // then ONE wait and stream the 8 reads + PV MFMAs.
            #pragma unroll
            for (int ns = 0; ns < 2; ns++)
                #pragma unroll
                for (int ct = 0; ct < 8; ct++) {
                    float s0 = S[ct][ns][0], s1 = S[ct][ns][1];
                    float s2 = S[ct][ns][2], s3 = S[ct][ns][3];
                    uint w0, w1;
                    asm("v_cvt_pk_bf16_f32 %0, %1, %2" : "=v"(w0) : "v"(s0), "v"(s1));
                    asm("v_cvt_pk_bf16_f32 %0, %1, %2" : "=v"(w1) : "v"(s2), "v"(s3));
                    uint2 o; o.x = w0; o.y = w1;
                    *(uint2*)&Ps[wave][ns][ct >> 1]
                        [ln * 34 + (ct & 1) * 16 + quad * 4] = o;
                }

            #pragma unroll
            for (int p = 0; p < 4; p++)
                #pragma unroll
                for (int ns = 0; ns < 2; ns++) {
                    B8 pfr; pfr.u = *(const uint4*)&Ps[wave][ns][p]
                        [ln * 34 + quad * 8];
                    #pragma unroll
                    for (int ctd = 0; ctd < 4; ctd++)
                        Oacc[ctd][ns] = __builtin_amdgcn_mfma_f32_16x16x32_bf16(
                            vfr[ctd][p].f, pfr.f, Oacc[ctd][ns], 0, 0, 0);
                    Lacc[ns] = __builtin_amdgcn_mfma_f32_16x16x32_bf16(
                        ones.f, pfr.f, Lacc[ns], 0, 0, 0);
                }
            cur ^= 1;
        }

        // epilogue: bf16 attn_out [B*T][C]; lane ln = token, regs = d
        #pragma unroll
        for (int ns = 0; ns < 2; ns++) {
            float inv = 1.0f / Lacc[ns][0];
            int token = q0 + wave * 32 + ns * 16 + ln;
            ushort* dst = Ob + ((size_t)(b_ * Tn + token)) * Cn + h * 64;
            #pragma unroll
            for (int ctd = 0; ctd < 4; ctd++) {
                ushort4 o;
                #pragma unroll
                for (int reg = 0; reg < 4; reg++)
                    ((ushort*)&o)[reg] = f2bf(Oacc[ctd][ns][reg] * inv);
                *(ushort4*)&dst[ctd * 16 + quad * 4] = o;
            }
        }
    }
    #undef STAGE_K
}

// ---------------------------------------------------------------------------
extern "C" void kernel_launch(void* const* d_in, const int* in_sizes, int n_in,
                              void* d_out, int out_size, void* d_ws, size_t ws_size,
                              hipStream_t stream) {
    const float* X     = (const float*)d_in[0];
    const float* qkv_w = (const float*)d_in[1];
    const float* qkv_b = (const float*)d_in[2];
    const float* o_w   = (const float*)d_in[3];
    const float* o_b   = (const float*)d_in[4];
    float* out = (float*)d_out;

    const size_t BTC = (size_t)Bn * Tn * Cn;     // 8388608
    ushort* Xb  = (ushort*)d_ws;                 // bf16 [8192,1024]
    ushort* Wqt = Xb  + BTC;                     // bf16 [3072,1024]
    ushort* Wot = Wqt + 3 * Cn * Cn;             // bf16 [1024,1024]
    ushort* Qb  = Wot + Cn * Cn;                 // bf16 [B,H,T,D]
    ushort* Kb  = Qb  + BTC;
    ushort* Vtb = Kb  + BTC;                     // bf16 [B,H,D,T]
    ushort* Ao  = Vtb + BTC;                     // bf16 [B*T,C]

    // fused prep: y=0 cast (4096 blocks), y=1 qkv_w transpose (96*32=3072),
    // y=2 o_w transpose (32*32=1024). grid.x = max section size.
    prep_fused<<<dim3(4096, 3), 256, 0, stream>>>(X, qkv_w, o_w, Xb, Wqt, Wot);

    gemm_bt<1><<<dim3(3 * Cn / 128, 8192 / 128), 256, 0, stream>>>(
        Xb, Wqt, qkv_b, nullptr, Qb, Kb, Vtb);
    attn_mfma<<<dim3(Bn * Hn, 8), 256, 0, stream>>>(Qb, Kb, Vtb, Ao);
    gemm_bt<0><<<dim3(Cn / 128, 8192 / 128), 256, 0, stream>>>(
        Ao, Wot, o_b, out, nullptr, nullptr, nullptr);
}

// Round 10
// 264.626 us; speedup vs baseline: 1.5772x; 1.0195x over previous
//
#include <hip/hip_runtime.h>
#include <hip/hip_bf16.h>

// Problem constants
#define Bn 4
#define Tn 2048
#define Cn 1024
#define Hn 16
#define Dn 64
#define Kdim 1024

typedef __bf16 bf16x8 __attribute__((ext_vector_type(8)));
typedef float f32x4 __attribute__((ext_vector_type(4)));
union B8 { uint4 u; bf16x8 f; ushort s[8]; };

static __device__ __forceinline__ ushort f2bf(float x) {
    __hip_bfloat16 h = __float2bfloat16(x);
    return *(ushort*)&h;
}

#define AS1 __attribute__((address_space(1)))
#define AS3 __attribute__((address_space(3)))

static __device__ __forceinline__ void gload_lds16(const ushort* g, ushort* l) {
    __builtin_amdgcn_global_load_lds((AS1 const uint4*)(const void*)g,
                                     (AS3 uint4*)(void*)l, 16, 0, 0);
}

// ---------------------------------------------------------------------------
// Fused prep: grid.y selects section.
//  y==0 (4096 blocks): X fp32 -> bf16 (layout preserved)
//  y==1 (96x32 via blockIdx.x): qkv_w [K,3C] -> Wqt [3C,K] bf16
//  y==2 (32x32): o_w [K,C] -> Wot [C,K] bf16
// ---------------------------------------------------------------------------
__global__ __launch_bounds__(256) void prep_fused(
    const float* __restrict__ X, const float* __restrict__ qkv_w,
    const float* __restrict__ o_w,
    ushort* __restrict__ Xb, ushort* __restrict__ Wqt, ushort* __restrict__ Wot)
{
    if (blockIdx.y == 0) {
        int i = (blockIdx.x * 256 + threadIdx.x) * 8;
        float4 a = *(const float4*)&X[i];
        float4 b = *(const float4*)&X[i + 4];
        ushort4 o0, o1;
        o0.x = f2bf(a.x); o0.y = f2bf(a.y); o0.z = f2bf(a.z); o0.w = f2bf(a.w);
        o1.x = f2bf(b.x); o1.y = f2bf(b.y); o1.z = f2bf(b.z); o1.w = f2bf(b.w);
        *(ushort4*)&Xb[i] = o0;
        *(ushort4*)&Xb[i + 4] = o1;
        return;
    }
    // transpose sections
    const float* W; ushort* Wt; int N, bx;
    if (blockIdx.y == 1) { W = qkv_w; Wt = Wqt; N = 3 * Cn; bx = blockIdx.x; }
    else                 { W = o_w;   Wt = Wot; N = Cn;     bx = blockIdx.x; }
    if (bx >= (N / 32) * 32) return;
    const int n0 = (bx % (N / 32)) * 32, k0 = (bx / (N / 32)) * 32;
    __shared__ float Ls[32][33];
    const int tx = threadIdx.x & 31, ty = threadIdx.x >> 5;
    #pragma unroll
    for (int i = 0; i < 4; i++) {
        int r = ty + i * 8;
        Ls[r][tx] = W[(size_t)(k0 + r) * N + n0 + tx];
    }
    __syncthreads();
    #pragma unroll
    for (int i = 0; i < 4; i++) {
        int r = ty + i * 8;
        Wt[(size_t)(n0 + r) * Kdim + k0 + tx] = f2bf(Ls[tx][r]);
    }
}

// ---------------------------------------------------------------------------
// bf16 MFMA GEMM (m97 structure): C[M,N] = A[M,K] @ Bt[N,K]^T (+bias).
// Bijective XCD swizzle (T1): contiguous grid chunk per XCD -> A panel
// L2-resident per XCD. nwg % 8 == 0 (1536, 512).
// EPI 0: fp32 out + bias.
// EPI 1: bf16 Q[B,H,T,D] (pre-scaled by D^-0.5*log2(e)), K[B,H,T,D],
//        V^T[B,H,D,T]. Epilogue round-trips each wave's 64x64 tile through
//        LDS (XOR bank swizzle) -> fully coalesced uint4 global stores.
// ---------------------------------------------------------------------------
template <int EPI>
__global__ __launch_bounds__(256) void gemm_bt(
    const ushort* __restrict__ A, const ushort* __restrict__ Bt,
    const float* __restrict__ bias,
    float* __restrict__ Out, ushort* __restrict__ Qb,
    ushort* __restrict__ Kb, ushort* __restrict__ Vtb)
{
    // XCD-aware bijective swizzle: contiguous grid chunk per XCD.
    const int nbx = gridDim.x;
    const int nwg = nbx * gridDim.y;
    const int bid = blockIdx.y * nbx + blockIdx.x;
    const int cpx = nwg >> 3;                 // nwg % 8 == 0 for our grids
    const int wg  = (bid & 7) * cpx + (bid >> 3);
    const int m0 = (wg / nbx) * 128;
    const int n0 = (wg % nbx) * 128;
    const int t  = threadIdx.x;
    const int wave = t >> 6, lane = t & 63;
    const int ln = lane & 15, quad = lane >> 4;
    const int wm = wave >> 1, wn = wave & 1;

    __shared__ ushort As[128 * 64];
    __shared__ ushort Bs[128 * 64];

    f32x4 acc[4][4] = {};

    for (int k0 = 0; k0 < Kdim; k0 += 64) {
        __syncthreads();
        #pragma unroll
        for (int it = 0; it < 4; it++) {
            int c = it * 256 + wave * 64 + lane;
            int row = c >> 3, seg = c & 7;
            int gseg = seg ^ (row & 7);
            gload_lds16(&A [(size_t)(m0 + row) * Kdim + k0 + gseg * 8], &As[c * 8]);
            gload_lds16(&Bt[(size_t)(n0 + row) * Kdim + k0 + gseg * 8], &Bs[c * 8]);
        }
        __syncthreads();

        #pragma unroll
        for (int ks = 0; ks < 2; ks++) {
            bf16x8 af[4], bf[4];
            #pragma unroll
            for (int mm = 0; mm < 4; mm++) {
                int row = wm * 64 + mm * 16 + ln;
                int seg = (ks * 4 + quad) ^ (ln & 7);
                B8 tmp; tmp.u = *(const uint4*)&As[row * 64 + seg * 8];
                af[mm] = tmp.f;
            }
            #pragma unroll
            for (int nn = 0; nn < 4; nn++) {
                int row = wn * 64 + nn * 16 + ln;
                int seg = (ks * 4 + quad) ^ (ln & 7);
                B8 tmp; tmp.u = *(const uint4*)&Bs[row * 64 + seg * 8];
                bf[nn] = tmp.f;
            }
            #pragma unroll
            for (int mm = 0; mm < 4; mm++)
                #pragma unroll
                for (int nn = 0; nn < 4; nn++)
                    acc[mm][nn] = __builtin_amdgcn_mfma_f32_16x16x32_bf16(
                        af[mm], bf[nn], acc[mm][nn], 0, 0, 0);
        }
    }

    if (EPI == 0) {
        #pragma unroll
        for (int nn = 0; nn < 4; nn++) {
            int n = n0 + wn * 64 + nn * 16 + ln;
            float bv = bias[n];
            #pragma unroll
            for (int mm = 0; mm < 4; mm++) {
                int mbase = m0 + wm * 64 + mm * 16 + quad * 4;
                #pragma unroll
                for (int reg = 0; reg < 4; reg++)
                    Out[(size_t)(mbase + reg) * 1024 + n] = acc[mm][nn][reg] + bv;
            }
        }
    } else {
        const int nb = n0 + wn * 64;
        const int which = nb >> 10;            // 0=Q 1=K 2=V
        const int h = (nb & 1023) >> 6;
        const float scale = (which == 0) ? 0.125f * 1.44269504088896f : 1.0f;
        const int b_ = m0 >> 11;               // 128-row tile within one batch
        const int t0 = (m0 & 2047) + wm * 64;

        __syncthreads();   // fragments consumed; reuse As/Bs as transpose pads
        ushort* tile = ((wave & 2) ? Bs : As) + (wave & 1) * 4096;  // 64x64/wave

        if (which == 2) {
            // LDS tile [n=d][m=token] (XOR-swizzled), rows -> [B,H,D,T]
            #pragma unroll
            for (int nn = 0; nn < 4; nn++) {
                float bv = bias[nb + nn * 16 + ln];
                #pragma unroll
                for (int mm = 0; mm < 4; mm++)
                    #pragma unroll
                    for (int reg = 0; reg < 4; reg++) {
                        int m = mm * 16 + quad * 4 + reg;
                        int n = nn * 16 + ln;
                        tile[n * 64 + (m ^ (((n >> 1) & 7) * 8))] =
                            f2bf(acc[mm][nn][reg] + bv);
                    }
            }
            #pragma unroll
            for (int it = 0; it < 8; it++) {
                int idx = it * 64 + lane;
                int row = idx >> 3, seg = idx & 7;   // row = d, seg = token/8
                uint4 v = *(const uint4*)&tile[row * 64 +
                              ((seg * 8) ^ (((row >> 1) & 7) * 8))];
                *(uint4*)&Vtb[((size_t)((b_ * Hn + h) * Dn) + row) * Tn + t0 + seg * 8] = v;
            }
        } else {
            // LDS tile [m=token][n=d] (XOR-swizzled), rows -> [B,H,T,D]
            ushort* dst = (which == 0) ? Qb : Kb;
            #pragma unroll
            for (int nn = 0; nn < 4; nn++) {
                float bv = bias[nb + nn * 16 + ln];
                #pragma unroll
                for (int mm = 0; mm < 4; mm++)
                    #pragma unroll
                    for (int reg = 0; reg < 4; reg++) {
                        int m = mm * 16 + quad * 4 + reg;
                        int n = nn * 16 + ln;
                        tile[m * 64 + (n ^ (((m >> 1) & 7) * 8))] =
                            f2bf((acc[mm][nn][reg] + bv) * scale);
                    }
            }
            #pragma unroll
            for (int it = 0; it < 8; it++) {
                int idx = it * 64 + lane;
                int row = idx >> 3, seg = idx & 7;   // row = token, seg = d/8
                uint4 v = *(const uint4*)&tile[row * 64 +
                              ((seg * 8) ^ (((row >> 1) & 7) * 8))];
                *(uint4*)&dst[((size_t)((b_ * Hn + h) * Tn) + t0 + row) * Dn + seg * 8] = v;
            }
        }
    }
}

// ---------------------------------------------------------------------------
// Flash attention (r22 = r18 + V staged in LDS): 128-row q-tiles paired
// (15-y, y), grid (64,8) = 512 balanced blocks = 2/CU, 32 q per wave.
// KEY CHANGE: V^T fragments were loaded global->VGPR with NO wave term —
// all 4 waves fetched the identical 16KB V chunk (4x redundant L2 traffic,
// 160KB/CU/chunk = the dominant stall). V now staged ONCE per block into
// LDS (gload_lds, xor-swizzled source, same pattern as K); a mid-chunk
// __syncthreads() before PV publishes it (its vmcnt drain still leaves the
// K(kc+1) prefetch the full QK+softmax window to land). PV reads per-pass
// V-fragments from LDS (16 regs vs the old vfr[4][4]=64) -> arch register
// pressure drops, residual spill should vanish.
// Ps halved via ping-pong slots (r20 scheme, correctness-proven): batch-0
// P-writes land free across the mid-barrier; batch-1 pays one lgkm wait.
// LDS = Ks 32KB + Vs 16KB + Ps 17.4KB = 65.5KB -> 2 blocks/CU.
// Retained: batched P roundtrip, exp2-with-m_old + defer-max (THR=8),
// cvt_pk packing, ones-MFMA row-sum, tree max. No setprio (r19: -11us).
// ---------------------------------------------------------------------------
__global__ __launch_bounds__(256, 2) void attn_mfma(
    const ushort* __restrict__ Qb, const ushort* __restrict__ Kb,
    const ushort* __restrict__ Vtb, ushort* __restrict__ Ob)
{
    const int bh   = blockIdx.x;       // 0..63 (fastest-varying)
    const int yp   = blockIdx.y;       // 0..7: pair (15-yp, yp)
    const int t    = threadIdx.x;
    const int wave = t >> 6, lane = t & 63;
    const int ln   = lane & 15, quad = lane >> 4;

    __shared__ ushort Ks[2][128 * 64];       // [key][d], xor-swizzled segs
    __shared__ ushort Vs[64 * 128];          // [d][token], xor-swizzled segs
    __shared__ ushort Ps[4][2][2][16 * 34];  // [wave][slot][ns][q(16)*34]

    const ushort* KgB = Kb  + (size_t)bh * Tn * Dn;
    const ushort* VgB = Vtb + (size_t)bh * Dn * Tn;
    const int b_ = bh >> 4, h = bh & 15;

    // all-ones bf16 A-fragment for the l row-sum MFMA
    B8 ones;
    #pragma unroll
    for (int j = 0; j < 8; j++) ones.s[j] = 0x3F80;

    #define STAGE_K(kc, buf)                                                   \
        do {                                                                   \
            _Pragma("unroll")                                                  \
            for (int it = 0; it < 4; it++) {                                   \
                int c = it * 256 + wave * 64 + lane;                           \
                int row = c >> 3, seg = c & 7;                                 \
                int gs = seg ^ (row & 7);                                      \
                gload_lds16(&KgB[(size_t)((kc) * 128 + row) * Dn + gs * 8],    \
                            &Ks[buf][c * 8]);                                  \
            }                                                                  \
        } while (0)

    // V chunk 64 rows (d) x 128 cols (token) = 16KB; 16 segs/row,
    // source col-seg pre-swizzled so linear LDS + swizzled read pair up.
    #define STAGE_V(kc)                                                        \
        do {                                                                   \
            _Pragma("unroll")                                                  \
            for (int it = 0; it < 4; it++) {                                   \
                int c = it * 256 + wave * 64 + lane;                           \
                int row = c >> 4, seg = c & 15;                                \
                int gs = seg ^ (row & 7);                                      \
                gload_lds16(&VgB[(size_t)row * Tn + (kc) * 128 + gs * 8],      \
                            &Vs[c * 8]);                                       \
            }                                                                  \
        } while (0)

    // pack pass p's P (cvt_pk) and write to slot pp
    #define PACK_WRITE(p, pp)                                                  \
        do {                                                                   \
            _Pragma("unroll")                                                  \
            for (int ns = 0; ns < 2; ns++)                                     \
                _Pragma("unroll")                                              \
                for (int cth = 0; cth < 2; cth++) {                            \
                    int ct = (p) * 2 + cth;                                    \
                    float s0 = S[ct][ns][0], s1 = S[ct][ns][1];                \
                    float s2 = S[ct][ns][2], s3 = S[ct][ns][3];                \
                    uint w0, w1;                                               \
                    asm("v_cvt_pk_bf16_f32 %0, %1, %2"                         \
                        : "=v"(w0) : "v"(s0), "v"(s1));                        \
                    asm("v_cvt_pk_bf16_f32 %0, %1, %2"                         \
                        : "=v"(w1) : "v"(s2), "v"(s3));                        \
                    uint2 o; o.x = w0; o.y = w1;                               \
                    *(uint2*)&Ps[wave][pp][ns]                                 \
                        [ln * 34 + cth * 16 + quad * 4] = o;                   \
                }                                                              \
        } while (0)

    // PV pass p from slot pp: per-pass V frags from LDS (16 regs)
    #define PV_PASS(p, pp)                                                     \
        do {                                                                   \
            B8 vfrp[4];                                                        \
            _Pragma("unroll")                                                  \
            for (int ctd = 0; ctd < 4; ctd++)                                  \
                vfrp[ctd].u = *(const uint4*)&Vs[(ctd * 16 + ln) * 128 +       \
                    ((((p) * 4 + quad) ^ (ln & 7)) * 8)];                      \
            _Pragma("unroll")                                                  \
            for (int ns = 0; ns < 2; ns++) {                                   \
                B8 pfr; pfr.u = *(const uint4*)&Ps[wave][pp][ns]               \
                    [ln * 34 + quad * 8];                                      \
                _Pragma("unroll")                                              \
                for (int ctd = 0; ctd < 4; ctd++)                              \
                    Oacc[ctd][ns] = __builtin_amdgcn_mfma_f32_16x16x32_bf16(   \
                        vfrp[ctd].f, pfr.f, Oacc[ctd][ns], 0, 0, 0);           \
                Lacc[ns] = __builtin_amdgcn_mfma_f32_16x16x32_bf16(            \
                    ones.f, pfr.f, Lacc[ns], 0, 0, 0);                         \
            }                                                                  \
        } while (0)

    for (int pass = 0; pass < 2; pass++) {
        const int qt = pass ? yp : 15 - yp;
        if (pass) __syncthreads();     // protect Ks/Vs reuse from pass-0 readers

        int cur = 0;
        STAGE_K(0, 0);

        const int q0 = qt * 128;
        const ushort* Qg = Qb + ((size_t)bh * Tn + q0 + wave * 32) * Dn;
        bf16x8 qf[2][2];
        #pragma unroll
        for (int ns = 0; ns < 2; ns++)
            #pragma unroll
            for (int ks = 0; ks < 2; ks++) {
                B8 tmp; tmp.u = *(const uint4*)&Qg[(ns * 16 + ln) * 64 + ks * 32 + quad * 8];
                qf[ns][ks] = tmp.f;
            }

        f32x4 Oacc[4][2] = {};   // O^T [d-subtile][ns], lane ln = q
        f32x4 Lacc[2] = {};      // row-sum accumulator (rows replicated)
        float m_r[2] = {0.f, 0.f};   // init 0: exp2-first scheme needs finite S-m

        for (int kc = 0; kc <= qt; kc++) {
            __syncthreads();   // top: publishes K(kc); V buffer free (prior PV done)

            STAGE_V(kc);                             // V once per block -> LDS
            if (kc < qt) STAGE_K(kc + 1, cur ^ 1);   // prefetch next K chunk

            // S^T = K Q^T: rows = keys (128 = 8 ct), cols = q (32 = 2 ns)
            const ushort* Kc = Ks[cur];
            f32x4 S[8][2] = {};
            #pragma unroll
            for (int ks = 0; ks < 2; ks++)
                #pragma unroll
                for (int ct = 0; ct < 8; ct++) {
                    B8 a; a.u = *(const uint4*)&Kc[(ct * 16 + ln) * 64 +
                                                   (((ks * 4 + quad) ^ (ln & 7)) * 8)];
                    #pragma unroll
                    for (int ns = 0; ns < 2; ns++)
                        S[ct][ns] = __builtin_amdgcn_mfma_f32_16x16x32_bf16(
                            a.f, qf[ns][ks], S[ct][ns], 0, 0, 0);
                }

            if (kc == qt) {   // causal mask on diagonal chunk
                #pragma unroll
                for (int ct = 0; ct < 8; ct++) {
                    int keyl = ct * 16 + quad * 4;
                    #pragma unroll
                    for (int ns = 0; ns < 2; ns++) {
                        int ql = wave * 32 + ns * 16 + ln;
                        #pragma unroll
                        for (int reg = 0; reg < 4; reg++)
                            if (keyl + reg > ql) S[ct][ns][reg] = -1e30f;
                    }
                }
            }

            // per-lane chunk max (tree), reduce over quads
            float pm[2], m_old[2];
            #pragma unroll
            for (int ns = 0; ns < 2; ns++) {
                m_old[ns] = m_r[ns];
                float ctm[8];
                #pragma unroll
                for (int ct = 0; ct < 8; ct++)
                    ctm[ct] = fmaxf(fmaxf(S[ct][ns][0], S[ct][ns][1]),
                                    fmaxf(S[ct][ns][2], S[ct][ns][3]));
                float p = fmaxf(fmaxf(fmaxf(ctm[0], ctm[1]), fmaxf(ctm[2], ctm[3])),
                                fmaxf(fmaxf(ctm[4], ctm[5]), fmaxf(ctm[6], ctm[7])));
                p = fmaxf(p, __shfl_xor(p, 16));
                p = fmaxf(p, __shfl_xor(p, 32));
                pm[ns] = p;
            }

            // exp2 with OLD max — independent of the shuffle chain above.
            // Safe: S - m_old <= ~20 << 128 (m_old >= 0), masked -> exp2 -> 0.
            #pragma unroll
            for (int ns = 0; ns < 2; ns++)
                #pragma unroll
                for (int ct = 0; ct < 8; ct++)
                    #pragma unroll
                    for (int reg = 0; reg < 4; reg++)
                        S[ct][ns][reg] = exp2f(S[ct][ns][reg] - m_old[ns]);

            // defer-max: rescale only when some lane's max grew by > 8 (log2)
            bool need = (pm[0] > m_old[0] + 8.0f) | (pm[1] > m_old[1] + 8.0f);
            if (__any(need)) {
                #pragma unroll
                for (int ns = 0; ns < 2; ns++) {
                    float mn = fmaxf(m_old[ns], pm[ns]);
                    float alpha = exp2f(m_old[ns] - mn);
                    m_r[ns] = mn;
                    #pragma unroll
                    for (int ct = 0; ct < 8; ct++)
                        #pragma unroll
                        for (int reg = 0; reg < 4; reg++)
                            S[ct][ns][reg] *= alpha;
                    #pragma unroll
                    for (int ctd = 0; ctd < 4; ctd++)
                        Oacc[ctd][ns] *= alpha;
                    Lacc[ns] *= alpha;
                }
            }

            // batch 0 P-writes BEFORE the mid barrier (its lgkm drain covers
            // them for free); mid barrier also publishes Vs (vmcnt drain).
            PACK_WRITE(0, 0);
            PACK_WRITE(1, 1);
            __syncthreads();   // mid: Vs ready; K(kc+1) lands early (harmless)

            PV_PASS(0, 0);
            PV_PASS(1, 1);
            PACK_WRITE(2, 0);  // WAR-safe: DS ops per-wave in-order
            PACK_WRITE(3, 1);
            PV_PASS(2, 0);
            PV_PASS(3, 1);
            cur ^= 1;
        }

        // epilogue: bf16 attn_out [B*T][C]; lane ln = token, regs = d
        #pragma unroll
        for (int ns = 0; ns < 2; ns++) {
            float inv = 1.0f / Lacc[ns][0];
            int token = q0 + wave * 32 + ns * 16 + ln;
            ushort* dst = Ob + ((size_t)(b_ * Tn + token)) * Cn + h * 64;
            #pragma unroll
            for (int ctd = 0; ctd < 4; ctd++) {
                ushort4 o;
                #pragma unroll
                for (int reg = 0; reg < 4; reg++)
                    ((ushort*)&o)[reg] = f2bf(Oacc[ctd][ns][reg] * inv);
                *(ushort4*)&dst[ctd * 16 + quad * 4] = o;
            }
        }
    }
    #undef STAGE_K
    #undef STAGE_V
    #undef PACK_WRITE
    #undef PV_PASS
}

// ---------------------------------------------------------------------------
extern "C" void kernel_launch(void* const* d_in, const int* in_sizes, int n_in,
                              void* d_out, int out_size, void* d_ws, size_t ws_size,
                              hipStream_t stream) {
    const float* X     = (const float*)d_in[0];
    const float* qkv_w = (const float*)d_in[1];
    const float* qkv_b = (const float*)d_in[2];
    const float* o_w   = (const float*)d_in[3];
    const float* o_b   = (const float*)d_in[4];
    float* out = (float*)d_out;

    const size_t BTC = (size_t)Bn * Tn * Cn;     // 8388608
    ushort* Xb  = (ushort*)d_ws;                 // bf16 [8192,1024]
    ushort* Wqt = Xb  + BTC;                     // bf16 [3072,1024]
    ushort* Wot = Wqt + 3 * Cn * Cn;             // bf16 [1024,1024]
    ushort* Qb  = Wot + Cn * Cn;                 // bf16 [B,H,T,D]
    ushort* Kb  = Qb  + BTC;
    ushort* Vtb = Kb  + BTC;                     // bf16 [B,H,D,T]
    ushort* Ao  = Vtb + BTC;                     // bf16 [B*T,C]

    // fused prep: y=0 cast (4096 blocks), y=1 qkv_w transpose (96*32=3072),
    // y=2 o_w transpose (32*32=1024). grid.x = max section size.
    prep_fused<<<dim3(4096, 3), 256, 0, stream>>>(X, qkv_w, o_w, Xb, Wqt, Wot);

    gemm_bt<1><<<dim3(3 * Cn / 128, 8192 / 128), 256, 0, stream>>>(
        Xb, Wqt, qkv_b, nullptr, Qb, Kb, Vtb);
    attn_mfma<<<dim3(Bn * Hn, 8), 256, 0, stream>>>(Qb, Kb, Vtb, Ao);
    gemm_bt<0><<<dim3(Cn / 128, 8192 / 128), 256, 0, stream>>>(
        Ao, Wot, o_b, out, nullptr, nullptr, nullptr);
}

// Round 11
// 262.486 us; speedup vs baseline: 1.5900x; 1.0081x over previous
//
#include <hip/hip_runtime.h>
#include <hip/hip_bf16.h>

// Problem constants
#define Bn 4
#define Tn 2048
#define Cn 1024
#define Hn 16
#define Dn 64
#define Kdim 1024

typedef __bf16 bf16x8 __attribute__((ext_vector_type(8)));
typedef float f32x4 __attribute__((ext_vector_type(4)));
union B8 { uint4 u; bf16x8 f; ushort s[8]; };

static __device__ __forceinline__ ushort f2bf(float x) {
    __hip_bfloat16 h = __float2bfloat16(x);
    return *(ushort*)&h;
}

#define AS1 __attribute__((address_space(1)))
#define AS3 __attribute__((address_space(3)))

static __device__ __forceinline__ void gload_lds16(const ushort* g, ushort* l) {
    __builtin_amdgcn_global_load_lds((AS1 const uint4*)(const void*)g,
                                     (AS3 uint4*)(void*)l, 16, 0, 0);
}

// ---------------------------------------------------------------------------
// Fused prep: grid.y selects section.
//  y==0 (4096 blocks): X fp32 -> bf16 (layout preserved)
//  y==1 (96x32 via blockIdx.x): qkv_w [K,3C] -> Wqt [3C,K] bf16
//  y==2 (32x32): o_w [K,C] -> Wot [C,K] bf16
// ---------------------------------------------------------------------------
__global__ __launch_bounds__(256) void prep_fused(
    const float* __restrict__ X, const float* __restrict__ qkv_w,
    const float* __restrict__ o_w,
    ushort* __restrict__ Xb, ushort* __restrict__ Wqt, ushort* __restrict__ Wot)
{
    if (blockIdx.y == 0) {
        int i = (blockIdx.x * 256 + threadIdx.x) * 8;
        float4 a = *(const float4*)&X[i];
        float4 b = *(const float4*)&X[i + 4];
        ushort4 o0, o1;
        o0.x = f2bf(a.x); o0.y = f2bf(a.y); o0.z = f2bf(a.z); o0.w = f2bf(a.w);
        o1.x = f2bf(b.x); o1.y = f2bf(b.y); o1.z = f2bf(b.z); o1.w = f2bf(b.w);
        *(ushort4*)&Xb[i] = o0;
        *(ushort4*)&Xb[i + 4] = o1;
        return;
    }
    // transpose sections
    const float* W; ushort* Wt; int N, bx;
    if (blockIdx.y == 1) { W = qkv_w; Wt = Wqt; N = 3 * Cn; bx = blockIdx.x; }
    else                 { W = o_w;   Wt = Wot; N = Cn;     bx = blockIdx.x; }
    if (bx >= (N / 32) * 32) return;
    const int n0 = (bx % (N / 32)) * 32, k0 = (bx / (N / 32)) * 32;
    __shared__ float Ls[32][33];
    const int tx = threadIdx.x & 31, ty = threadIdx.x >> 5;
    #pragma unroll
    for (int i = 0; i < 4; i++) {
        int r = ty + i * 8;
        Ls[r][tx] = W[(size_t)(k0 + r) * N + n0 + tx];
    }
    __syncthreads();
    #pragma unroll
    for (int i = 0; i < 4; i++) {
        int r = ty + i * 8;
        Wt[(size_t)(n0 + r) * Kdim + k0 + tx] = f2bf(Ls[tx][r]);
    }
}

// ---------------------------------------------------------------------------
// bf16 MFMA GEMM (m97 structure): C[M,N] = A[M,K] @ Bt[N,K]^T (+bias).
// Bijective XCD swizzle (T1): contiguous grid chunk per XCD -> A panel
// L2-resident per XCD. nwg % 8 == 0 (1536, 512).
// EPI 0: fp32 out + bias.
// EPI 1: bf16 Q[B,H,T,D] (pre-scaled by D^-0.5*log2(e)), K[B,H,T,D],
//        V^T[B,H,D,T]. Epilogue round-trips each wave's 64x64 tile through
//        LDS (XOR bank swizzle) -> fully coalesced uint4 global stores.
// ---------------------------------------------------------------------------
template <int EPI>
__global__ __launch_bounds__(256) void gemm_bt(
    const ushort* __restrict__ A, const ushort* __restrict__ Bt,
    const float* __restrict__ bias,
    float* __restrict__ Out, ushort* __restrict__ Qb,
    ushort* __restrict__ Kb, ushort* __restrict__ Vtb)
{
    // XCD-aware bijective swizzle: contiguous grid chunk per XCD.
    const int nbx = gridDim.x;
    const int nwg = nbx * gridDim.y;
    const int bid = blockIdx.y * nbx + blockIdx.x;
    const int cpx = nwg >> 3;                 // nwg % 8 == 0 for our grids
    const int wg  = (bid & 7) * cpx + (bid >> 3);
    const int m0 = (wg / nbx) * 128;
    const int n0 = (wg % nbx) * 128;
    const int t  = threadIdx.x;
    const int wave = t >> 6, lane = t & 63;
    const int ln = lane & 15, quad = lane >> 4;
    const int wm = wave >> 1, wn = wave & 1;

    __shared__ ushort As[128 * 64];
    __shared__ ushort Bs[128 * 64];

    f32x4 acc[4][4] = {};

    for (int k0 = 0; k0 < Kdim; k0 += 64) {
        __syncthreads();
        #pragma unroll
        for (int it = 0; it < 4; it++) {
            int c = it * 256 + wave * 64 + lane;
            int row = c >> 3, seg = c & 7;
            int gseg = seg ^ (row & 7);
            gload_lds16(&A [(size_t)(m0 + row) * Kdim + k0 + gseg * 8], &As[c * 8]);
            gload_lds16(&Bt[(size_t)(n0 + row) * Kdim + k0 + gseg * 8], &Bs[c * 8]);
        }
        __syncthreads();

        #pragma unroll
        for (int ks = 0; ks < 2; ks++) {
            bf16x8 af[4], bf[4];
            #pragma unroll
            for (int mm = 0; mm < 4; mm++) {
                int row = wm * 64 + mm * 16 + ln;
                int seg = (ks * 4 + quad) ^ (ln & 7);
                B8 tmp; tmp.u = *(const uint4*)&As[row * 64 + seg * 8];
                af[mm] = tmp.f;
            }
            #pragma unroll
            for (int nn = 0; nn < 4; nn++) {
                int row = wn * 64 + nn * 16 + ln;
                int seg = (ks * 4 + quad) ^ (ln & 7);
                B8 tmp; tmp.u = *(const uint4*)&Bs[row * 64 + seg * 8];
                bf[nn] = tmp.f;
            }
            #pragma unroll
            for (int mm = 0; mm < 4; mm++)
                #pragma unroll
                for (int nn = 0; nn < 4; nn++)
                    acc[mm][nn] = __builtin_amdgcn_mfma_f32_16x16x32_bf16(
                        af[mm], bf[nn], acc[mm][nn], 0, 0, 0);
        }
    }

    if (EPI == 0) {
        #pragma unroll
        for (int nn = 0; nn < 4; nn++) {
            int n = n0 + wn * 64 + nn * 16 + ln;
            float bv = bias[n];
            #pragma unroll
            for (int mm = 0; mm < 4; mm++) {
                int mbase = m0 + wm * 64 + mm * 16 + quad * 4;
                #pragma unroll
                for (int reg = 0; reg < 4; reg++)
                    Out[(size_t)(mbase + reg) * 1024 + n] = acc[mm][nn][reg] + bv;
            }
        }
    } else {
        const int nb = n0 + wn * 64;
        const int which = nb >> 10;            // 0=Q 1=K 2=V
        const int h = (nb & 1023) >> 6;
        const float scale = (which == 0) ? 0.125f * 1.44269504088896f : 1.0f;
        const int b_ = m0 >> 11;               // 128-row tile within one batch
        const int t0 = (m0 & 2047) + wm * 64;

        __syncthreads();   // fragments consumed; reuse As/Bs as transpose pads
        ushort* tile = ((wave & 2) ? Bs : As) + (wave & 1) * 4096;  // 64x64/wave

        if (which == 2) {
            // LDS tile [n=d][m=token] (XOR-swizzled), rows -> [B,H,D,T]
            #pragma unroll
            for (int nn = 0; nn < 4; nn++) {
                float bv = bias[nb + nn * 16 + ln];
                #pragma unroll
                for (int mm = 0; mm < 4; mm++)
                    #pragma unroll
                    for (int reg = 0; reg < 4; reg++) {
                        int m = mm * 16 + quad * 4 + reg;
                        int n = nn * 16 + ln;
                        tile[n * 64 + (m ^ (((n >> 1) & 7) * 8))] =
                            f2bf(acc[mm][nn][reg] + bv);
                    }
            }
            #pragma unroll
            for (int it = 0; it < 8; it++) {
                int idx = it * 64 + lane;
                int row = idx >> 3, seg = idx & 7;   // row = d, seg = token/8
                uint4 v = *(const uint4*)&tile[row * 64 +
                              ((seg * 8) ^ (((row >> 1) & 7) * 8))];
                *(uint4*)&Vtb[((size_t)((b_ * Hn + h) * Dn) + row) * Tn + t0 + seg * 8] = v;
            }
        } else {
            // LDS tile [m=token][n=d] (XOR-swizzled), rows -> [B,H,T,D]
            ushort* dst = (which == 0) ? Qb : Kb;
            #pragma unroll
            for (int nn = 0; nn < 4; nn++) {
                float bv = bias[nb + nn * 16 + ln];
                #pragma unroll
                for (int mm = 0; mm < 4; mm++)
                    #pragma unroll
                    for (int reg = 0; reg < 4; reg++) {
                        int m = mm * 16 + quad * 4 + reg;
                        int n = nn * 16 + ln;
                        tile[m * 64 + (n ^ (((m >> 1) & 7) * 8))] =
                            f2bf((acc[mm][nn][reg] + bv) * scale);
                    }
            }
            #pragma unroll
            for (int it = 0; it < 8; it++) {
                int idx = it * 64 + lane;
                int row = idx >> 3, seg = idx & 7;   // row = token, seg = d/8
                uint4 v = *(const uint4*)&tile[row * 64 +
                              ((seg * 8) ^ (((row >> 1) & 7) * 8))];
                *(uint4*)&dst[((size_t)((b_ * Hn + h) * Tn) + t0 + row) * Dn + seg * 8] = v;
            }
        }
    }
}

// ---------------------------------------------------------------------------
// Flash attention (r23 = r22 with two scheduling fixes):
//  FIX 1: STAGE_K(kc+1) issued AFTER the mid barrier (r22 issued it before,
//         so the mid barrier's vmcnt(0) force-drained the K prefetch; now
//         the mid barrier drains only STAGE_V — issued ~1200cyc earlier,
//         free — and K lands during PV, drained at the next top barrier).
//  FIX 2: batch-1 P pack/writes interleaved between PV passes
//         (PV0, PACK2, PV1, PACK3, PV2, PV3) to maximize write->read
//         distance before the lgkm waits.
// Structure (r22): 128-row q-tiles paired (15-y,y), grid (64,8) = 2/CU;
// V staged once/block in LDS (was 4x-redundant global); Ps ping-pong
// 2-slot; LDS = Ks 32 + Vs 16 + Ps 17.4 = 65.5KB. No spill (VGPR 112).
// Retained: batched P roundtrip, exp2-with-m_old + defer-max (THR=8),
// cvt_pk packing, ones-MFMA row-sum, tree max. No setprio (r19: -11us).
// ---------------------------------------------------------------------------
__global__ __launch_bounds__(256, 2) void attn_mfma(
    const ushort* __restrict__ Qb, const ushort* __restrict__ Kb,
    const ushort* __restrict__ Vtb, ushort* __restrict__ Ob)
{
    const int bh   = blockIdx.x;       // 0..63 (fastest-varying)
    const int yp   = blockIdx.y;       // 0..7: pair (15-yp, yp)
    const int t    = threadIdx.x;
    const int wave = t >> 6, lane = t & 63;
    const int ln   = lane & 15, quad = lane >> 4;

    __shared__ ushort Ks[2][128 * 64];       // [key][d], xor-swizzled segs
    __shared__ ushort Vs[64 * 128];          // [d][token], xor-swizzled segs
    __shared__ ushort Ps[4][2][2][16 * 34];  // [wave][slot][ns][q(16)*34]

    const ushort* KgB = Kb  + (size_t)bh * Tn * Dn;
    const ushort* VgB = Vtb + (size_t)bh * Dn * Tn;
    const int b_ = bh >> 4, h = bh & 15;

    // all-ones bf16 A-fragment for the l row-sum MFMA
    B8 ones;
    #pragma unroll
    for (int j = 0; j < 8; j++) ones.s[j] = 0x3F80;

    #define STAGE_K(kc, buf)                                                   \
        do {                                                                   \
            _Pragma("unroll")                                                  \
            for (int it = 0; it < 4; it++) {                                   \
                int c = it * 256 + wave * 64 + lane;                           \
                int row = c >> 3, seg = c & 7;                                 \
                int gs = seg ^ (row & 7);                                      \
                gload_lds16(&KgB[(size_t)((kc) * 128 + row) * Dn + gs * 8],    \
                            &Ks[buf][c * 8]);                                  \
            }                                                                  \
        } while (0)

    // V chunk 64 rows (d) x 128 cols (token) = 16KB; 16 segs/row,
    // source col-seg pre-swizzled so linear LDS + swizzled read pair up.
    #define STAGE_V(kc)                                                        \
        do {                                                                   \
            _Pragma("unroll")                                                  \
            for (int it = 0; it < 4; it++) {                                   \
                int c = it * 256 + wave * 64 + lane;                           \
                int row = c >> 4, seg = c & 15;                                \
                int gs = seg ^ (row & 7);                                      \
                gload_lds16(&VgB[(size_t)row * Tn + (kc) * 128 + gs * 8],      \
                            &Vs[c * 8]);                                       \
            }                                                                  \
        } while (0)

    // pack pass p's P (cvt_pk) and write to slot pp
    #define PACK_WRITE(p, pp)                                                  \
        do {                                                                   \
            _Pragma("unroll")                                                  \
            for (int ns = 0; ns < 2; ns++)                                     \
                _Pragma("unroll")                                              \
                for (int cth = 0; cth < 2; cth++) {                            \
                    int ct = (p) * 2 + cth;                                    \
                    float s0 = S[ct][ns][0], s1 = S[ct][ns][1];                \
                    float s2 = S[ct][ns][2], s3 = S[ct][ns][3];                \
                    uint w0, w1;                                               \
                    asm("v_cvt_pk_bf16_f32 %0, %1, %2"                         \
                        : "=v"(w0) : "v"(s0), "v"(s1));                        \
                    asm("v_cvt_pk_bf16_f32 %0, %1, %2"                         \
                        : "=v"(w1) : "v"(s2), "v"(s3));                        \
                    uint2 o; o.x = w0; o.y = w1;                               \
                    *(uint2*)&Ps[wave][pp][ns]                                 \
                        [ln * 34 + cth * 16 + quad * 4] = o;                   \
                }                                                              \
        } while (0)

    // PV pass p from slot pp: per-pass V frags from LDS (16 regs)
    #define PV_PASS(p, pp)                                                     \
        do {                                                                   \
            B8 vfrp[4];                                                        \
            _Pragma("unroll")                                                  \
            for (int ctd = 0; ctd < 4; ctd++)                                  \
                vfrp[ctd].u = *(const uint4*)&Vs[(ctd * 16 + ln) * 128 +       \
                    ((((p) * 4 + quad) ^ (ln & 7)) * 8)];                      \
            _Pragma("unroll")                                                  \
            for (int ns = 0; ns < 2; ns++) {                                   \
                B8 pfr; pfr.u = *(const uint4*)&Ps[wave][pp][ns]               \
                    [ln * 34 + quad * 8];                                      \
                _Pragma("unroll")                                              \
                for (int ctd = 0; ctd < 4; ctd++)                              \
                    Oacc[ctd][ns] = __builtin_amdgcn_mfma_f32_16x16x32_bf16(   \
                        vfrp[ctd].f, pfr.f, Oacc[ctd][ns], 0, 0, 0);           \
                Lacc[ns] = __builtin_amdgcn_mfma_f32_16x16x32_bf16(            \
                    ones.f, pfr.f, Lacc[ns], 0, 0, 0);                         \
            }                                                                  \
        } while (0)

    for (int pass = 0; pass < 2; pass++) {
        const int qt = pass ? yp : 15 - yp;
        if (pass) __syncthreads();     // protect Ks/Vs reuse from pass-0 readers

        int cur = 0;
        STAGE_K(0, 0);

        const int q0 = qt * 128;
        const ushort* Qg = Qb + ((size_t)bh * Tn + q0 + wave * 32) * Dn;
        bf16x8 qf[2][2];
        #pragma unroll
        for (int ns = 0; ns < 2; ns++)
            #pragma unroll
            for (int ks = 0; ks < 2; ks++) {
                B8 tmp; tmp.u = *(const uint4*)&Qg[(ns * 16 + ln) * 64 + ks * 32 + quad * 8];
                qf[ns][ks] = tmp.f;
            }

        f32x4 Oacc[4][2] = {};   // O^T [d-subtile][ns], lane ln = q
        f32x4 Lacc[2] = {};      // row-sum accumulator (rows replicated)
        float m_r[2] = {0.f, 0.f};   // init 0: exp2-first scheme needs finite S-m

        for (int kc = 0; kc <= qt; kc++) {
            __syncthreads();   // top: publishes K(kc); drains prior-chunk K+V

            STAGE_V(kc);       // V once per block -> LDS (drained at mid bar)

            // S^T = K Q^T: rows = keys (128 = 8 ct), cols = q (32 = 2 ns)
            const ushort* Kc = Ks[cur];
            f32x4 S[8][2] = {};
            #pragma unroll
            for (int ks = 0; ks < 2; ks++)
                #pragma unroll
                for (int ct = 0; ct < 8; ct++) {
                    B8 a; a.u = *(const uint4*)&Kc[(ct * 16 + ln) * 64 +
                                                   (((ks * 4 + quad) ^ (ln & 7)) * 8)];
                    #pragma unroll
                    for (int ns = 0; ns < 2; ns++)
                        S[ct][ns] = __builtin_amdgcn_mfma_f32_16x16x32_bf16(
                            a.f, qf[ns][ks], S[ct][ns], 0, 0, 0);
                }

            if (kc == qt) {   // causal mask on diagonal chunk
                #pragma unroll
                for (int ct = 0; ct < 8; ct++) {
                    int keyl = ct * 16 + quad * 4;
                    #pragma unroll
                    for (int ns = 0; ns < 2; ns++) {
                        int ql = wave * 32 + ns * 16 + ln;
                        #pragma unroll
                        for (int reg = 0; reg < 4; reg++)
                            if (keyl + reg > ql) S[ct][ns][reg] = -1e30f;
                    }
                }
            }

            // per-lane chunk max (tree), reduce over quads
            float pm[2], m_old[2];
            #pragma unroll
            for (int ns = 0; ns < 2; ns++) {
                m_old[ns] = m_r[ns];
                float ctm[8];
                #pragma unroll
                for (int ct = 0; ct < 8; ct++)
                    ctm[ct] = fmaxf(fmaxf(S[ct][ns][0], S[ct][ns][1]),
                                    fmaxf(S[ct][ns][2], S[ct][ns][3]));
                float p = fmaxf(fmaxf(fmaxf(ctm[0], ctm[1]), fmaxf(ctm[2], ctm[3])),
                                fmaxf(fmaxf(ctm[4], ctm[5]), fmaxf(ctm[6], ctm[7])));
                p = fmaxf(p, __shfl_xor(p, 16));
                p = fmaxf(p, __shfl_xor(p, 32));
                pm[ns] = p;
            }

            // exp2 with OLD max — independent of the shuffle chain above.
            // Safe: S - m_old <= ~20 << 128 (m_old >= 0), masked -> exp2 -> 0.
            #pragma unroll
            for (int ns = 0; ns < 2; ns++)
                #pragma unroll
                for (int ct = 0; ct < 8; ct++)
                    #pragma unroll
                    for (int reg = 0; reg < 4; reg++)
                        S[ct][ns][reg] = exp2f(S[ct][ns][reg] - m_old[ns]);

            // defer-max: rescale only when some lane's max grew by > 8 (log2)
            bool need = (pm[0] > m_old[0] + 8.0f) | (pm[1] > m_old[1] + 8.0f);
            if (__any(need)) {
                #pragma unroll
                for (int ns = 0; ns < 2; ns++) {
                    float mn = fmaxf(m_old[ns], pm[ns]);
                    float alpha = exp2f(m_old[ns] - mn);
                    m_r[ns] = mn;
                    #pragma unroll
                    for (int ct = 0; ct < 8; ct++)
                        #pragma unroll
                        for (int reg = 0; reg < 4; reg++)
                            S[ct][ns][reg] *= alpha;
                    #pragma unroll
                    for (int ctd = 0; ctd < 4; ctd++)
                        Oacc[ctd][ns] *= alpha;
                    Lacc[ns] *= alpha;
                }
            }

            // batch-0 P-writes BEFORE the mid barrier (its lgkm drain covers
            // them for free); mid barrier publishes Vs (vmcnt drain of the
            // V stage only — K prefetch not yet issued).
            PACK_WRITE(0, 0);
            PACK_WRITE(1, 1);
            __syncthreads();   // mid: Vs ready

            if (kc < qt) STAGE_K(kc + 1, cur ^ 1);   // K prefetch: lands in PV

            PV_PASS(0, 0);
            PACK_WRITE(2, 0);  // WAR-safe: DS ops per-wave in-order
            PV_PASS(1, 1);
            PACK_WRITE(3, 1);
            PV_PASS(2, 0);
            PV_PASS(3, 1);
            cur ^= 1;
        }

        // epilogue: bf16 attn_out [B*T][C]; lane ln = token, regs = d
        #pragma unroll
        for (int ns = 0; ns < 2; ns++) {
            float inv = 1.0f / Lacc[ns][0];
            int token = q0 + wave * 32 + ns * 16 + ln;
            ushort* dst = Ob + ((size_t)(b_ * Tn + token)) * Cn + h * 64;
            #pragma unroll
            for (int ctd = 0; ctd < 4; ctd++) {
                ushort4 o;
                #pragma unroll
                for (int reg = 0; reg < 4; reg++)
                    ((ushort*)&o)[reg] = f2bf(Oacc[ctd][ns][reg] * inv);
                *(ushort4*)&dst[ctd * 16 + quad * 4] = o;
            }
        }
    }
    #undef STAGE_K
    #undef STAGE_V
    #undef PACK_WRITE
    #undef PV_PASS
}

// ---------------------------------------------------------------------------
extern "C" void kernel_launch(void* const* d_in, const int* in_sizes, int n_in,
                              void* d_out, int out_size, void* d_ws, size_t ws_size,
                              hipStream_t stream) {
    const float* X     = (const float*)d_in[0];
    const float* qkv_w = (const float*)d_in[1];
    const float* qkv_b = (const float*)d_in[2];
    const float* o_w   = (const float*)d_in[3];
    const float* o_b   = (const float*)d_in[4];
    float* out = (float*)d_out;

    const size_t BTC = (size_t)Bn * Tn * Cn;     // 8388608
    ushort* Xb  = (ushort*)d_ws;                 // bf16 [8192,1024]
    ushort* Wqt = Xb  + BTC;                     // bf16 [3072,1024]
    ushort* Wot = Wqt + 3 * Cn * Cn;             // bf16 [1024,1024]
    ushort* Qb  = Wot + Cn * Cn;                 // bf16 [B,H,T,D]
    ushort* Kb  = Qb  + BTC;
    ushort* Vtb = Kb  + BTC;                     // bf16 [B,H,D,T]
    ushort* Ao  = Vtb + BTC;                     // bf16 [B*T,C]

    // fused prep: y=0 cast (4096 blocks), y=1 qkv_w transpose (96*32=3072),
    // y=2 o_w transpose (32*32=1024). grid.x = max section size.
    prep_fused<<<dim3(4096, 3), 256, 0, stream>>>(X, qkv_w, o_w, Xb, Wqt, Wot);

    gemm_bt<1><<<dim3(3 * Cn / 128, 8192 / 128), 256, 0, stream>>>(
        Xb, Wqt, qkv_b, nullptr, Qb, Kb, Vtb);
    attn_mfma<<<dim3(Bn * Hn, 8), 256, 0, stream>>>(Qb, Kb, Vtb, Ao);
    gemm_bt<0><<<dim3(Cn / 128, 8192 / 128), 256, 0, stream>>>(
        Ao, Wot, o_b, out, nullptr, nullptr, nullptr);
}

// Round 13
// 262.141 us; speedup vs baseline: 1.5921x; 1.0013x over previous
//
#include <hip/hip_runtime.h>
#include <hip/hip_bf16.h>

// Problem constants
#define Bn 4
#define Tn 2048
#define Cn 1024
#define Hn 16
#define Dn 64
#define Kdim 1024

typedef __bf16 bf16x8 __attribute__((ext_vector_type(8)));
typedef float f32x4 __attribute__((ext_vector_type(4)));
union B8 { uint4 u; bf16x8 f; ushort s[8]; };

static __device__ __forceinline__ ushort f2bf(float x) {
    __hip_bfloat16 h = __float2bfloat16(x);
    return *(ushort*)&h;
}

#define AS1 __attribute__((address_space(1)))
#define AS3 __attribute__((address_space(3)))

static __device__ __forceinline__ void gload_lds16(const ushort* g, ushort* l) {
    __builtin_amdgcn_global_load_lds((AS1 const uint4*)(const void*)g,
                                     (AS3 uint4*)(void*)l, 16, 0, 0);
}

// ---------------------------------------------------------------------------
// Fused prep, 1-D grid (8192 blocks, no idle no-op blocks):
//  blk 0..4095:    X fp32 -> bf16 (layout preserved)
//  blk 4096..7167: qkv_w [K,3C] -> Wqt [3C,K] bf16   (96x32 tiles)
//  blk 7168..8191: o_w [K,C] -> Wot [C,K] bf16       (32x32 tiles)
// Index mapping identical to the r23 guarded 2-D version.
// ---------------------------------------------------------------------------
__global__ __launch_bounds__(256) void prep_fused(
    const float* __restrict__ X, const float* __restrict__ qkv_w,
    const float* __restrict__ o_w,
    ushort* __restrict__ Xb, ushort* __restrict__ Wqt, ushort* __restrict__ Wot)
{
    const int blk = blockIdx.x;
    if (blk < 4096) {
        int i = (blk * 256 + threadIdx.x) * 8;
        float4 a = *(const float4*)&X[i];
        float4 b = *(const float4*)&X[i + 4];
        ushort4 o0, o1;
        o0.x = f2bf(a.x); o0.y = f2bf(a.y); o0.z = f2bf(a.z); o0.w = f2bf(a.w);
        o1.x = f2bf(b.x); o1.y = f2bf(b.y); o1.z = f2bf(b.z); o1.w = f2bf(b.w);
        *(ushort4*)&Xb[i] = o0;
        *(ushort4*)&Xb[i + 4] = o1;
        return;
    }
    // transpose sections
    const float* W; ushort* Wt; int N, bx;
    if (blk < 7168) { W = qkv_w; Wt = Wqt; N = 3 * Cn; bx = blk - 4096; }
    else            { W = o_w;   Wt = Wot; N = Cn;     bx = blk - 7168; }
    const int n0 = (bx % (N / 32)) * 32, k0 = (bx / (N / 32)) * 32;
    __shared__ float Ls[32][33];
    const int tx = threadIdx.x & 31, ty = threadIdx.x >> 5;
    #pragma unroll
    for (int i = 0; i < 4; i++) {
        int r = ty + i * 8;
        Ls[r][tx] = W[(size_t)(k0 + r) * N + n0 + tx];
    }
    __syncthreads();
    #pragma unroll
    for (int i = 0; i < 4; i++) {
        int r = ty + i * 8;
        Wt[(size_t)(n0 + r) * Kdim + k0 + tx] = f2bf(Ls[tx][r]);
    }
}

// ---------------------------------------------------------------------------
// bf16 MFMA GEMM (m97 structure): C[M,N] = A[M,K] @ Bt[N,K]^T (+bias).
// Bijective XCD swizzle (T1): contiguous grid chunk per XCD -> A panel
// L2-resident per XCD. nwg % 8 == 0 (1536, 512).
// EPI 0: fp32 out + bias.
// EPI 1: bf16 Q[B,H,T,D] (pre-scaled by D^-0.5*log2(e)), K[B,H,T,D],
//        V^T[B,H,D,T]. Epilogue round-trips each wave's 64x64 tile through
//        LDS (XOR bank swizzle) -> fully coalesced uint4 global stores.
// ---------------------------------------------------------------------------
template <int EPI>
__global__ __launch_bounds__(256) void gemm_bt(
    const ushort* __restrict__ A, const ushort* __restrict__ Bt,
    const float* __restrict__ bias,
    float* __restrict__ Out, ushort* __restrict__ Qb,
    ushort* __restrict__ Kb, ushort* __restrict__ Vtb)
{
    // XCD-aware bijective swizzle: contiguous grid chunk per XCD.
    const int nbx = gridDim.x;
    const int nwg = nbx * gridDim.y;
    const int bid = blockIdx.y * nbx + blockIdx.x;
    const int cpx = nwg >> 3;                 // nwg % 8 == 0 for our grids
    const int wg  = (bid & 7) * cpx + (bid >> 3);
    const int m0 = (wg / nbx) * 128;
    const int n0 = (wg % nbx) * 128;
    const int t  = threadIdx.x;
    const int wave = t >> 6, lane = t & 63;
    const int ln = lane & 15, quad = lane >> 4;
    const int wm = wave >> 1, wn = wave & 1;

    __shared__ ushort As[128 * 64];
    __shared__ ushort Bs[128 * 64];

    f32x4 acc[4][4] = {};

    for (int k0 = 0; k0 < Kdim; k0 += 64) {
        __syncthreads();
        #pragma unroll
        for (int it = 0; it < 4; it++) {
            int c = it * 256 + wave * 64 + lane;
            int row = c >> 3, seg = c & 7;
            int gseg = seg ^ (row & 7);
            gload_lds16(&A [(size_t)(m0 + row) * Kdim + k0 + gseg * 8], &As[c * 8]);
            gload_lds16(&Bt[(size_t)(n0 + row) * Kdim + k0 + gseg * 8], &Bs[c * 8]);
        }
        __syncthreads();

        #pragma unroll
        for (int ks = 0; ks < 2; ks++) {
            bf16x8 af[4], bf[4];
            #pragma unroll
            for (int mm = 0; mm < 4; mm++) {
                int row = wm * 64 + mm * 16 + ln;
                int seg = (ks * 4 + quad) ^ (ln & 7);
                B8 tmp; tmp.u = *(const uint4*)&As[row * 64 + seg * 8];
                af[mm] = tmp.f;
            }
            #pragma unroll
            for (int nn = 0; nn < 4; nn++) {
                int row = wn * 64 + nn * 16 + ln;
                int seg = (ks * 4 + quad) ^ (ln & 7);
                B8 tmp; tmp.u = *(const uint4*)&Bs[row * 64 + seg * 8];
                bf[nn] = tmp.f;
            }
            #pragma unroll
            for (int mm = 0; mm < 4; mm++)
                #pragma unroll
                for (int nn = 0; nn < 4; nn++)
                    acc[mm][nn] = __builtin_amdgcn_mfma_f32_16x16x32_bf16(
                        af[mm], bf[nn], acc[mm][nn], 0, 0, 0);
        }
    }

    if (EPI == 0) {
        #pragma unroll
        for (int nn = 0; nn < 4; nn++) {
            int n = n0 + wn * 64 + nn * 16 + ln;
            float bv = bias[n];
            #pragma unroll
            for (int mm = 0; mm < 4; mm++) {
                int mbase = m0 + wm * 64 + mm * 16 + quad * 4;
                #pragma unroll
                for (int reg = 0; reg < 4; reg++)
                    Out[(size_t)(mbase + reg) * 1024 + n] = acc[mm][nn][reg] + bv;
            }
        }
    } else {
        const int nb = n0 + wn * 64;
        const int which = nb >> 10;            // 0=Q 1=K 2=V
        const int h = (nb & 1023) >> 6;
        const float scale = (which == 0) ? 0.125f * 1.44269504088896f : 1.0f;
        const int b_ = m0 >> 11;               // 128-row tile within one batch
        const int t0 = (m0 & 2047) + wm * 64;

        __syncthreads();   // fragments consumed; reuse As/Bs as transpose pads
        ushort* tile = ((wave & 2) ? Bs : As) + (wave & 1) * 4096;  // 64x64/wave

        if (which == 2) {
            // LDS tile [n=d][m=token] (XOR-swizzled), rows -> [B,H,D,T]
            #pragma unroll
            for (int nn = 0; nn < 4; nn++) {
                float bv = bias[nb + nn * 16 + ln];
                #pragma unroll
                for (int mm = 0; mm < 4; mm++)
                    #pragma unroll
                    for (int reg = 0; reg < 4; reg++) {
                        int m = mm * 16 + quad * 4 + reg;
                        int n = nn * 16 + ln;
                        tile[n * 64 + (m ^ (((n >> 1) & 7) * 8))] =
                            f2bf(acc[mm][nn][reg] + bv);
                    }
            }
            #pragma unroll
            for (int it = 0; it < 8; it++) {
                int idx = it * 64 + lane;
                int row = idx >> 3, seg = idx & 7;   // row = d, seg = token/8
                uint4 v = *(const uint4*)&tile[row * 64 +
                              ((seg * 8) ^ (((row >> 1) & 7) * 8))];
                *(uint4*)&Vtb[((size_t)((b_ * Hn + h) * Dn) + row) * Tn + t0 + seg * 8] = v;
            }
        } else {
            // LDS tile [m=token][n=d] (XOR-swizzled), rows -> [B,H,T,D]
            ushort* dst = (which == 0) ? Qb : Kb;
            #pragma unroll
            for (int nn = 0; nn < 4; nn++) {
                float bv = bias[nb + nn * 16 + ln];
                #pragma unroll
                for (int mm = 0; mm < 4; mm++)
                    #pragma unroll
                    for (int reg = 0; reg < 4; reg++) {
                        int m = mm * 16 + quad * 4 + reg;
                        int n = nn * 16 + ln;
                        tile[m * 64 + (n ^ (((m >> 1) & 7) * 8))] =
                            f2bf((acc[mm][nn][reg] + bv) * scale);
                    }
            }
            #pragma unroll
            for (int it = 0; it < 8; it++) {
                int idx = it * 64 + lane;
                int row = idx >> 3, seg = idx & 7;   // row = token, seg = d/8
                uint4 v = *(const uint4*)&tile[row * 64 +
                              ((seg * 8) ^ (((row >> 1) & 7) * 8))];
                *(uint4*)&dst[((size_t)((b_ * Hn + h) * Tn) + t0 + row) * Dn + seg * 8] = v;
            }
        }
    }
}

// ---------------------------------------------------------------------------
// Flash attention (r25 = r23 verbatim, the verified 90.7us best):
// 128-row q-tiles paired (15-y,y), grid (64,8) = 512 balanced = 2/CU.
// V staged once/block in LDS; STAGE_K(kc+1) issued AFTER the mid barrier
// (so the mid barrier's vmcnt(0) drains only the V stage, and the K
// prefetch lands during PV, drained at the next top barrier); batch-1
// P pack/writes interleaved between PV passes for write->read distance.
// Ps ping-pong 2-slot; LDS = Ks 32 + Vs 16 + Ps 17.4 = 65.5KB; VGPR 116,
// zero spill (WRITE_SIZE == ideal 16.39MB).
// Retained: batched P roundtrip, exp2-with-m_old + defer-max (THR=8),
// cvt_pk packing, ones-MFMA row-sum, tree max. No setprio (r19: -11us).
// SETTLED: (256,3)/(256,4) spill both register-file halves (r20/r14-16);
// cooperative mega-kernel fails under graph capture (r24: output zeros).
// ---------------------------------------------------------------------------
__global__ __launch_bounds__(256, 2) void attn_mfma(
    const ushort* __restrict__ Qb, const ushort* __restrict__ Kb,
    const ushort* __restrict__ Vtb, ushort* __restrict__ Ob)
{
    const int bh   = blockIdx.x;       // 0..63 (fastest-varying)
    const int yp   = blockIdx.y;       // 0..7: pair (15-yp, yp)
    const int t    = threadIdx.x;
    const int wave = t >> 6, lane = t & 63;
    const int ln   = lane & 15, quad = lane >> 4;

    __shared__ ushort Ks[2][128 * 64];       // [key][d], xor-swizzled segs
    __shared__ ushort Vs[64 * 128];          // [d][token], xor-swizzled segs
    __shared__ ushort Ps[4][2][2][16 * 34];  // [wave][slot][ns][q(16)*34]

    const ushort* KgB = Kb  + (size_t)bh * Tn * Dn;
    const ushort* VgB = Vtb + (size_t)bh * Dn * Tn;
    const int b_ = bh >> 4, h = bh & 15;

    // all-ones bf16 A-fragment for the l row-sum MFMA
    B8 ones;
    #pragma unroll
    for (int j = 0; j < 8; j++) ones.s[j] = 0x3F80;

    #define STAGE_K(kc, buf)                                                   \
        do {                                                                   \
            _Pragma("unroll")                                                  \
            for (int it = 0; it < 4; it++) {                                   \
                int c = it * 256 + wave * 64 + lane;                           \
                int row = c >> 3, seg = c & 7;                                 \
                int gs = seg ^ (row & 7);                                      \
                gload_lds16(&KgB[(size_t)((kc) * 128 + row) * Dn + gs * 8],    \
                            &Ks[buf][c * 8]);                                  \
            }                                                                  \
        } while (0)

    // V chunk 64 rows (d) x 128 cols (token) = 16KB; 16 segs/row,
    // source col-seg pre-swizzled so linear LDS + swizzled read pair up.
    #define STAGE_V(kc)                                                        \
        do {                                                                   \
            _Pragma("unroll")                                                  \
            for (int it = 0; it < 4; it++) {                                   \
                int c = it * 256 + wave * 64 + lane;                           \
                int row = c >> 4, seg = c & 15;                                \
                int gs = seg ^ (row & 7);                                      \
                gload_lds16(&VgB[(size_t)row * Tn + (kc) * 128 + gs * 8],      \
                            &Vs[c * 8]);                                       \
            }                                                                  \
        } while (0)

    // pack pass p's P (cvt_pk) and write to slot pp
    #define PACK_WRITE(p, pp)                                                  \
        do {                                                                   \
            _Pragma("unroll")                                                  \
            for (int ns = 0; ns < 2; ns++)                                     \
                _Pragma("unroll")                                              \
                for (int cth = 0; cth < 2; cth++) {                            \
                    int ct = (p) * 2 + cth;                                    \
                    float s0 = S[ct][ns][0], s1 = S[ct][ns][1];                \
                    float s2 = S[ct][ns][2], s3 = S[ct][ns][3];                \
                    uint w0, w1;                                               \
                    asm("v_cvt_pk_bf16_f32 %0, %1, %2"                         \
                        : "=v"(w0) : "v"(s0), "v"(s1));                        \
                    asm("v_cvt_pk_bf16_f32 %0, %1, %2"                         \
                        : "=v"(w1) : "v"(s2), "v"(s3));                        \
                    uint2 o; o.x = w0; o.y = w1;                               \
                    *(uint2*)&Ps[wave][pp][ns]                                 \
                        [ln * 34 + cth * 16 + quad * 4] = o;                   \
                }                                                              \
        } while (0)

    // PV pass p from slot pp: per-pass V frags from LDS (16 regs)
    #define PV_PASS(p, pp)                                                     \
        do {                                                                   \
            B8 vfrp[4];                                                        \
            _Pragma("unroll")                                                  \
            for (int ctd = 0; ctd < 4; ctd++)                                  \
                vfrp[ctd].u = *(const uint4*)&Vs[(ctd * 16 + ln) * 128 +       \
                    ((((p) * 4 + quad) ^ (ln & 7)) * 8)];                      \
            _Pragma("unroll")                                                  \
            for (int ns = 0; ns < 2; ns++) {                                   \
                B8 pfr; pfr.u = *(const uint4*)&Ps[wave][pp][ns]               \
                    [ln * 34 + quad * 8];                                      \
                _Pragma("unroll")                                              \
                for (int ctd = 0; ctd < 4; ctd++)                              \
                    Oacc[ctd][ns] = __builtin_amdgcn_mfma_f32_16x16x32_bf16(   \
                        vfrp[ctd].f, pfr.f, Oacc[ctd][ns], 0, 0, 0);           \
                Lacc[ns] = __builtin_amdgcn_mfma_f32_16x16x32_bf16(            \
                    ones.f, pfr.f, Lacc[ns], 0, 0, 0);                         \
            }                                                                  \
        } while (0)

    for (int pass = 0; pass < 2; pass++) {
        const int qt = pass ? yp : 15 - yp;
        if (pass) __syncthreads();     // protect Ks/Vs reuse from pass-0 readers

        int cur = 0;
        STAGE_K(0, 0);

        const int q0 = qt * 128;
        const ushort* Qg = Qb + ((size_t)bh * Tn + q0 + wave * 32) * Dn;
        bf16x8 qf[2][2];
        #pragma unroll
        for (int ns = 0; ns < 2; ns++)
            #pragma unroll
            for (int ks = 0; ks < 2; ks++) {
                B8 tmp; tmp.u = *(const uint4*)&Qg[(ns * 16 + ln) * 64 + ks * 32 + quad * 8];
                qf[ns][ks] = tmp.f;
            }

        f32x4 Oacc[4][2] = {};   // O^T [d-subtile][ns], lane ln = q
        f32x4 Lacc[2] = {};      // row-sum accumulator (rows replicated)
        float m_r[2] = {0.f, 0.f};   // init 0: exp2-first scheme needs finite S-m

        for (int kc = 0; kc <= qt; kc++) {
            __syncthreads();   // top: publishes K(kc); drains prior-chunk K+V

            STAGE_V(kc);       // V once per block -> LDS (drained at mid bar)

            // S^T = K Q^T: rows = keys (128 = 8 ct), cols = q (32 = 2 ns)
            const ushort* Kc = Ks[cur];
            f32x4 S[8][2] = {};
            #pragma unroll
            for (int ks = 0; ks < 2; ks++)
                #pragma unroll
                for (int ct = 0; ct < 8; ct++) {
                    B8 a; a.u = *(const uint4*)&Kc[(ct * 16 + ln) * 64 +
                                                   (((ks * 4 + quad) ^ (ln & 7)) * 8)];
                    #pragma unroll
                    for (int ns = 0; ns < 2; ns++)
                        S[ct][ns] = __builtin_amdgcn_mfma_f32_16x16x32_bf16(
                            a.f, qf[ns][ks], S[ct][ns], 0, 0, 0);
                }

            if (kc == qt) {   // causal mask on diagonal chunk
                #pragma unroll
                for (int ct = 0; ct < 8; ct++) {
                    int keyl = ct * 16 + quad * 4;
                    #pragma unroll
                    for (int ns = 0; ns < 2; ns++) {
                        int ql = wave * 32 + ns * 16 + ln;
                        #pragma unroll
                        for (int reg = 0; reg < 4; reg++)
                            if (keyl + reg > ql) S[ct][ns][reg] = -1e30f;
                    }
                }
            }

            // per-lane chunk max (tree), reduce over quads
            float pm[2], m_old[2];
            #pragma unroll
            for (int ns = 0; ns < 2; ns++) {
                m_old[ns] = m_r[ns];
                float ctm[8];
                #pragma unroll
                for (int ct = 0; ct < 8; ct++)
                    ctm[ct] = fmaxf(fmaxf(S[ct][ns][0], S[ct][ns][1]),
                                    fmaxf(S[ct][ns][2], S[ct][ns][3]));
                float p = fmaxf(fmaxf(fmaxf(ctm[0], ctm[1]), fmaxf(ctm[2], ctm[3])),
                                fmaxf(fmaxf(ctm[4], ctm[5]), fmaxf(ctm[6], ctm[7])));
                p = fmaxf(p, __shfl_xor(p, 16));
                p = fmaxf(p, __shfl_xor(p, 32));
                pm[ns] = p;
            }

            // exp2 with OLD max — independent of the shuffle chain above.
            // Safe: S - m_old <= ~20 << 128 (m_old >= 0), masked -> exp2 -> 0.
            #pragma unroll
            for (int ns = 0; ns < 2; ns++)
                #pragma unroll
                for (int ct = 0; ct < 8; ct++)
                    #pragma unroll
                    for (int reg = 0; reg < 4; reg++)
                        S[ct][ns][reg] = exp2f(S[ct][ns][reg] - m_old[ns]);

            // defer-max: rescale only when some lane's max grew by > 8 (log2)
            bool need = (pm[0] > m_old[0] + 8.0f) | (pm[1] > m_old[1] + 8.0f);
            if (__any(need)) {
                #pragma unroll
                for (int ns = 0; ns < 2; ns++) {
                    float mn = fmaxf(m_old[ns], pm[ns]);
                    float alpha = exp2f(m_old[ns] - mn);
                    m_r[ns] = mn;
                    #pragma unroll
                    for (int ct = 0; ct < 8; ct++)
                        #pragma unroll
                        for (int reg = 0; reg < 4; reg++)
                            S[ct][ns][reg] *= alpha;
                    #pragma unroll
                    for (int ctd = 0; ctd < 4; ctd++)
                        Oacc[ctd][ns] *= alpha;
                    Lacc[ns] *= alpha;
                }
            }

            // batch-0 P-writes BEFORE the mid barrier (its lgkm drain covers
            // them for free); mid barrier publishes Vs (vmcnt drain of the
            // V stage only — K prefetch not yet issued).
            PACK_WRITE(0, 0);
            PACK_WRITE(1, 1);
            __syncthreads();   // mid: Vs ready

            if (kc < qt) STAGE_K(kc + 1, cur ^ 1);   // K prefetch: lands in PV

            PV_PASS(0, 0);
            PACK_WRITE(2, 0);  // WAR-safe: DS ops per-wave in-order
            PV_PASS(1, 1);
            PACK_WRITE(3, 1);
            PV_PASS(2, 0);
            PV_PASS(3, 1);
            cur ^= 1;
        }

        // epilogue: bf16 attn_out [B*T][C]; lane ln = token, regs = d
        #pragma unroll
        for (int ns = 0; ns < 2; ns++) {
            float inv = 1.0f / Lacc[ns][0];
            int token = q0 + wave * 32 + ns * 16 + ln;
            ushort* dst = Ob + ((size_t)(b_ * Tn + token)) * Cn + h * 64;
            #pragma unroll
            for (int ctd = 0; ctd < 4; ctd++) {
                ushort4 o;
                #pragma unroll
                for (int reg = 0; reg < 4; reg++)
                    ((ushort*)&o)[reg] = f2bf(Oacc[ctd][ns][reg] * inv);
                *(ushort4*)&dst[ctd * 16 + quad * 4] = o;
            }
        }
    }
    #undef STAGE_K
    #undef STAGE_V
    #undef PACK_WRITE
    #undef PV_PASS
}

// ---------------------------------------------------------------------------
extern "C" void kernel_launch(void* const* d_in, const int* in_sizes, int n_in,
                              void* d_out, int out_size, void* d_ws, size_t ws_size,
                              hipStream_t stream) {
    const float* X     = (const float*)d_in[0];
    const float* qkv_w = (const float*)d_in[1];
    const float* qkv_b = (const float*)d_in[2];
    const float* o_w   = (const float*)d_in[3];
    const float* o_b   = (const float*)d_in[4];
    float* out = (float*)d_out;

    const size_t BTC = (size_t)Bn * Tn * Cn;     // 8388608
    ushort* Xb  = (ushort*)d_ws;                 // bf16 [8192,1024]
    ushort* Wqt = Xb  + BTC;                     // bf16 [3072,1024]
    ushort* Wot = Wqt + 3 * Cn * Cn;             // bf16 [1024,1024]
    ushort* Qb  = Wot + Cn * Cn;                 // bf16 [B,H,T,D]
    ushort* Kb  = Qb  + BTC;
    ushort* Vtb = Kb  + BTC;                     // bf16 [B,H,D,T]
    ushort* Ao  = Vtb + BTC;                     // bf16 [B*T,C]

    // 1-D prep: 4096 cast + 3072 qkv-w transpose + 1024 o_w transpose
    prep_fused<<<dim3(8192), 256, 0, stream>>>(X, qkv_w, o_w, Xb, Wqt, Wot);

    gemm_bt<1><<<dim3(3 * Cn / 128, 8192 / 128), 256, 0, stream>>>(
        Xb, Wqt, qkv_b, nullptr, Qb, Kb, Vtb);
    attn_mfma<<<dim3(Bn * Hn, 8), 256, 0, stream>>>(Qb, Kb, Vtb, Ao);
    gemm_bt<0><<<dim3(Cn / 128, 8192 / 128), 256, 0, stream>>>(
        Ao, Wot, o_b, out, nullptr, nullptr, nullptr);
}